// Round 1
// baseline (779.953 us; speedup 1.0000x reference)
//
#include <hip/hip_runtime.h>
#include <math.h>

#define H 2048
#define S 2048
#define NH 32
#define HD 64
#define DFF 8192

typedef __attribute__((ext_vector_type(4))) float f32x4;
typedef __attribute__((ext_vector_type(8))) short short8;

static __device__ __forceinline__ ushort f2bf(float f) {
  unsigned u = __float_as_uint(f);
  u += 0x7fff + ((u >> 16) & 1);
  return (ushort)(u >> 16);
}

// ---------------- transpose + cast fp32 -> bf16 ----------------
// W: [K][N] fp32 row-major; Wt: [N][K] bf16 (ushort bits)
__global__ __launch_bounds__(256) void transpose_cast_kernel(
    const float* __restrict__ W, ushort* __restrict__ Wt, int K, int N) {
  __shared__ ushort tile[32][33];
  int n0 = blockIdx.x * 32, k0 = blockIdx.y * 32;
  int tx = threadIdx.x, ty = threadIdx.y;
#pragma unroll
  for (int i = 0; i < 4; i++) {
    int k = ty * 4 + i;
    tile[k][tx] = f2bf(W[(size_t)(k0 + k) * N + n0 + tx]);
  }
  __syncthreads();
#pragma unroll
  for (int i = 0; i < 4; i++) {
    int n = ty * 4 + i;
    Wt[(size_t)(n0 + n) * K + k0 + tx] = tile[tx][n];
  }
}

// ---------------- LayerNorm fp32 -> bf16 ----------------
__global__ __launch_bounds__(256) void ln_kernel(
    const float* __restrict__ x, const float* __restrict__ w,
    const float* __restrict__ b, ushort* __restrict__ out) {
  int row = blockIdx.x, t = threadIdx.x;
  const float4* xr = reinterpret_cast<const float4*>(x + (size_t)row * H);
  float4 v0 = xr[t * 2], v1 = xr[t * 2 + 1];
  float s = v0.x + v0.y + v0.z + v0.w + v1.x + v1.y + v1.z + v1.w;
  float q = v0.x * v0.x + v0.y * v0.y + v0.z * v0.z + v0.w * v0.w +
            v1.x * v1.x + v1.y * v1.y + v1.z * v1.z + v1.w * v1.w;
#pragma unroll
  for (int off = 32; off > 0; off >>= 1) {
    s += __shfl_down(s, off, 64);
    q += __shfl_down(q, off, 64);
  }
  __shared__ float sm[8];
  int lane = t & 63, wv = t >> 6;
  if (lane == 0) { sm[wv] = s; sm[wv + 4] = q; }
  __syncthreads();
  s = sm[0] + sm[1] + sm[2] + sm[3];
  q = sm[4] + sm[5] + sm[6] + sm[7];
  float mu = s * (1.0f / H);
  float var = q * (1.0f / H) - mu * mu;
  float rs = rsqrtf(var + 1e-5f);
  const float4* wr = reinterpret_cast<const float4*>(w);
  const float4* br = reinterpret_cast<const float4*>(b);
  float4 w0 = wr[t * 2], w1v = wr[t * 2 + 1], b0 = br[t * 2], b1v = br[t * 2 + 1];
  short8 pk;
  pk[0] = (short)f2bf((v0.x - mu) * rs * w0.x + b0.x);
  pk[1] = (short)f2bf((v0.y - mu) * rs * w0.y + b0.y);
  pk[2] = (short)f2bf((v0.z - mu) * rs * w0.z + b0.z);
  pk[3] = (short)f2bf((v0.w - mu) * rs * w0.w + b0.w);
  pk[4] = (short)f2bf((v1.x - mu) * rs * w1v.x + b1v.x);
  pk[5] = (short)f2bf((v1.y - mu) * rs * w1v.y + b1v.y);
  pk[6] = (short)f2bf((v1.z - mu) * rs * w1v.z + b1v.z);
  pk[7] = (short)f2bf((v1.w - mu) * rs * w1v.w + b1v.w);
  *reinterpret_cast<short8*>(out + (size_t)row * H + t * 8) = pk;
}

// ---------------- bf16 MFMA GEMM: C = A[M,K] @ Bt[N,K]^T + bias ----------------
// MODE 0: outb = bf16((acc+bias)*scale)
// MODE 1: outb = bf16(gelu(acc+bias))
// MODE 2: outf = residual + acc + bias   (fp32)
template <int MODE>
__global__ __launch_bounds__(256) void gemm_kernel(
    const ushort* __restrict__ A, const ushort* __restrict__ Bt,
    const float* __restrict__ bias, const float* __restrict__ residual,
    ushort* __restrict__ outb, float* __restrict__ outf,
    int M, int N, int K, float scale) {
  __shared__ __align__(16) ushort As[128 * 32];
  __shared__ __align__(16) ushort Bs[128 * 32];
  int tid = threadIdx.x;
  int lane = tid & 63, wave = tid >> 6;
  int m0 = blockIdx.x * 128, n0 = blockIdx.y * 128;
  int wm = (wave >> 1) * 64, wn = (wave & 1) * 64;
  int lm = lane & 15, kg = lane >> 4;

  f32x4 acc[4][4] = {};

  int crow = tid >> 2;
  int ck8 = (tid & 3) * 8;
  const ushort* a0p = A + (size_t)(m0 + crow) * K + ck8;
  const ushort* a1p = A + (size_t)(m0 + 64 + crow) * K + ck8;
  const ushort* b0p = Bt + (size_t)(n0 + crow) * K + ck8;
  const ushort* b1p = Bt + (size_t)(n0 + 64 + crow) * K + ck8;
  ushort* asd0 = &As[crow * 32 + ck8];
  ushort* asd1 = &As[(crow + 64) * 32 + ck8];
  ushort* bsd0 = &Bs[crow * 32 + ck8];
  ushort* bsd1 = &Bs[(crow + 64) * 32 + ck8];

  for (int k0 = 0; k0 < K; k0 += 32) {
    short8 a0 = *reinterpret_cast<const short8*>(a0p + k0);
    short8 a1 = *reinterpret_cast<const short8*>(a1p + k0);
    short8 b0 = *reinterpret_cast<const short8*>(b0p + k0);
    short8 b1 = *reinterpret_cast<const short8*>(b1p + k0);
    __syncthreads();
    *reinterpret_cast<short8*>(asd0) = a0;
    *reinterpret_cast<short8*>(asd1) = a1;
    *reinterpret_cast<short8*>(bsd0) = b0;
    *reinterpret_cast<short8*>(bsd1) = b1;
    __syncthreads();
    short8 af[4], bfr[4];
#pragma unroll
    for (int i = 0; i < 4; i++)
      af[i] = *reinterpret_cast<const short8*>(&As[(wm + i * 16 + lm) * 32 + kg * 8]);
#pragma unroll
    for (int j = 0; j < 4; j++)
      bfr[j] = *reinterpret_cast<const short8*>(&Bs[(wn + j * 16 + lm) * 32 + kg * 8]);
#pragma unroll
    for (int i = 0; i < 4; i++)
#pragma unroll
      for (int j = 0; j < 4; j++)
        acc[i][j] = __builtin_amdgcn_mfma_f32_16x16x32_bf16(af[i], bfr[j], acc[i][j], 0, 0, 0);
  }

#pragma unroll
  for (int i = 0; i < 4; i++) {
#pragma unroll
    for (int j = 0; j < 4; j++) {
#pragma unroll
      for (int r = 0; r < 4; r++) {
        int row = m0 + wm + i * 16 + kg * 4 + r;
        int col = n0 + wn + j * 16 + lm;
        float v = acc[i][j][r] + bias[col];
        size_t idx = (size_t)row * N + col;
        if (MODE == 0) {
          outb[idx] = f2bf(v * scale);
        } else if (MODE == 1) {
          outb[idx] = f2bf(0.5f * v * (1.0f + erff(v * 0.70710678118f)));
        } else {
          outf[idx] = residual[idx] + v;
        }
      }
    }
  }
}

// ---------------- causal flash attention ----------------
// Q,K,V: [S,H] bf16 (head h at cols h*64..h*64+63), Q pre-scaled. ctx: [S,H] bf16.
__global__ __launch_bounds__(256) void attn_kernel(
    const ushort* __restrict__ Q, const ushort* __restrict__ Kb,
    const ushort* __restrict__ Vb, ushort* __restrict__ ctx) {
  __shared__ __align__(16) ushort Ks[64 * 64];
  __shared__ __align__(16) ushort Vt[64 * 64];
  __shared__ __align__(16) ushort Ps[4 * 16 * 64];
  int qb = blockIdx.x, h = blockIdx.y;
  int tid = threadIdx.x, lane = tid & 63, w = tid >> 6;
  int lm = lane & 15, kg = lane >> 4;

  short8 qa[2];
  {
    const ushort* qp = Q + (size_t)(qb * 64 + w * 16 + lm) * H + h * 64 + kg * 8;
    qa[0] = *reinterpret_cast<const short8*>(qp);
    qa[1] = *reinterpret_cast<const short8*>(qp + 32);
  }

  float m_run[4], l_run[4];
  f32x4 o_acc[4] = {};
#pragma unroll
  for (int r = 0; r < 4; r++) { m_run[r] = -1e30f; l_run[r] = 0.f; }

  int skey = tid >> 3;
  int sd8 = (tid & 7) * 8;

  for (int kb = 0; kb <= qb; kb++) {
    __syncthreads();
    {
      const ushort* kp0 = Kb + (size_t)(kb * 64 + skey) * H + h * 64 + sd8;
      const ushort* kp1 = Kb + (size_t)(kb * 64 + skey + 32) * H + h * 64 + sd8;
      short8 k0v = *reinterpret_cast<const short8*>(kp0);
      short8 k1v = *reinterpret_cast<const short8*>(kp1);
      *reinterpret_cast<short8*>(&Ks[skey * 64 + sd8]) = k0v;
      *reinterpret_cast<short8*>(&Ks[(skey + 32) * 64 + sd8]) = k1v;
      const ushort* vp0 = Vb + (size_t)(kb * 64 + skey) * H + h * 64 + sd8;
      const ushort* vp1 = Vb + (size_t)(kb * 64 + skey + 32) * H + h * 64 + sd8;
      short8 v0v = *reinterpret_cast<const short8*>(vp0);
      short8 v1v = *reinterpret_cast<const short8*>(vp1);
#pragma unroll
      for (int i = 0; i < 8; i++) {
        Vt[(sd8 + i) * 64 + skey] = (ushort)v0v[i];
        Vt[(sd8 + i) * 64 + skey + 32] = (ushort)v1v[i];
      }
    }
    __syncthreads();

    f32x4 sacc[4] = {};
#pragma unroll
    for (int j = 0; j < 4; j++) {
#pragma unroll
      for (int ks = 0; ks < 2; ks++) {
        short8 kf = *reinterpret_cast<const short8*>(&Ks[(j * 16 + lm) * 64 + ks * 32 + kg * 8]);
        sacc[j] = __builtin_amdgcn_mfma_f32_16x16x32_bf16(qa[ks], kf, sacc[j], 0, 0, 0);
      }
    }
    if (kb == qb) {
#pragma unroll
      for (int j = 0; j < 4; j++) {
        int key = j * 16 + lm;
#pragma unroll
        for (int r = 0; r < 4; r++) {
          int row = w * 16 + kg * 4 + r;
          if (key > row) sacc[j][r] = -1e30f;
        }
      }
    }
#pragma unroll
    for (int r = 0; r < 4; r++) {
      float t = fmaxf(fmaxf(sacc[0][r], sacc[1][r]), fmaxf(sacc[2][r], sacc[3][r]));
      t = fmaxf(t, __shfl_xor(t, 1, 64));
      t = fmaxf(t, __shfl_xor(t, 2, 64));
      t = fmaxf(t, __shfl_xor(t, 4, 64));
      t = fmaxf(t, __shfl_xor(t, 8, 64));
      float mnew = fmaxf(m_run[r], t);
      float sc = expf(m_run[r] - mnew);
      m_run[r] = mnew;
      float ps = 0.f;
#pragma unroll
      for (int j = 0; j < 4; j++) {
        float p = expf(sacc[j][r] - mnew);
        sacc[j][r] = p;
        ps += p;
      }
      ps += __shfl_xor(ps, 1, 64);
      ps += __shfl_xor(ps, 2, 64);
      ps += __shfl_xor(ps, 4, 64);
      ps += __shfl_xor(ps, 8, 64);
      l_run[r] = l_run[r] * sc + ps;
#pragma unroll
      for (int jd = 0; jd < 4; jd++) o_acc[jd][r] *= sc;
    }
#pragma unroll
    for (int j = 0; j < 4; j++)
#pragma unroll
      for (int r = 0; r < 4; r++)
        Ps[w * 1024 + (kg * 4 + r) * 64 + j * 16 + lm] = f2bf(sacc[j][r]);
    __syncthreads();
    short8 pa[2];
    pa[0] = *reinterpret_cast<const short8*>(&Ps[w * 1024 + lm * 64 + kg * 8]);
    pa[1] = *reinterpret_cast<const short8*>(&Ps[w * 1024 + lm * 64 + 32 + kg * 8]);
#pragma unroll
    for (int jd = 0; jd < 4; jd++) {
#pragma unroll
      for (int ks = 0; ks < 2; ks++) {
        short8 vf = *reinterpret_cast<const short8*>(&Vt[(jd * 16 + lm) * 64 + ks * 32 + kg * 8]);
        o_acc[jd] = __builtin_amdgcn_mfma_f32_16x16x32_bf16(pa[ks], vf, o_acc[jd], 0, 0, 0);
      }
    }
  }
#pragma unroll
  for (int jd = 0; jd < 4; jd++) {
#pragma unroll
    for (int r = 0; r < 4; r++) {
      int row = qb * 64 + w * 16 + kg * 4 + r;
      int col = h * 64 + jd * 16 + lm;
      ctx[(size_t)row * H + col] = f2bf(o_acc[jd][r] / l_run[r]);
    }
  }
}

extern "C" void kernel_launch(void* const* d_in, const int* in_sizes, int n_in,
                              void* d_out, int out_size, void* d_ws, size_t ws_size,
                              hipStream_t stream) {
  const float* x = (const float*)d_in[0];
  const float* ln1w = (const float*)d_in[2];
  const float* ln1b = (const float*)d_in[3];
  const float* wq = (const float*)d_in[4];
  const float* bq = (const float*)d_in[5];
  const float* wk = (const float*)d_in[6];
  const float* bk = (const float*)d_in[7];
  const float* wv = (const float*)d_in[8];
  const float* bv = (const float*)d_in[9];
  const float* wo = (const float*)d_in[10];
  const float* bo = (const float*)d_in[11];
  const float* w1 = (const float*)d_in[12];
  const float* b1 = (const float*)d_in[13];
  const float* w2 = (const float*)d_in[14];
  const float* b2 = (const float*)d_in[15];
  const float* ln2w = (const float*)d_in[16];
  const float* ln2b = (const float*)d_in[17];
  float* out = (float*)d_out;

  char* ws = (char*)d_ws;
  size_t off = 0;
  auto alloc = [&](size_t bytes) {
    char* p = ws + off;
    off += (bytes + 255) & ~(size_t)255;
    return p;
  };
  ushort* WT_Q = (ushort*)alloc((size_t)H * H * 2);
  ushort* WT_K = (ushort*)alloc((size_t)H * H * 2);
  ushort* WT_V = (ushort*)alloc((size_t)H * H * 2);
  ushort* WT_O = (ushort*)alloc((size_t)H * H * 2);
  ushort* WT_1 = (ushort*)alloc((size_t)DFF * H * 2);
  ushort* WT_2 = (ushort*)alloc((size_t)H * DFF * 2);
  ushort* H1 = (ushort*)alloc((size_t)S * H * 2);
  ushort* Qb = (ushort*)alloc((size_t)S * H * 2);
  ushort* Kbuf = (ushort*)alloc((size_t)S * H * 2);
  ushort* Vbuf = (ushort*)alloc((size_t)S * H * 2);
  ushort* CTX = (ushort*)alloc((size_t)S * H * 2);
  float* X1 = (float*)alloc((size_t)S * H * 4);
  ushort* H2 = (ushort*)alloc((size_t)S * H * 2);
  ushort* MID = (ushort*)alloc((size_t)S * DFF * 2);

  dim3 tt(32, 8);
  transpose_cast_kernel<<<dim3(H / 32, H / 32), tt, 0, stream>>>(wq, WT_Q, H, H);
  transpose_cast_kernel<<<dim3(H / 32, H / 32), tt, 0, stream>>>(wk, WT_K, H, H);
  transpose_cast_kernel<<<dim3(H / 32, H / 32), tt, 0, stream>>>(wv, WT_V, H, H);
  transpose_cast_kernel<<<dim3(H / 32, H / 32), tt, 0, stream>>>(wo, WT_O, H, H);
  transpose_cast_kernel<<<dim3(DFF / 32, H / 32), tt, 0, stream>>>(w1, WT_1, H, DFF);
  transpose_cast_kernel<<<dim3(H / 32, DFF / 32), tt, 0, stream>>>(w2, WT_2, DFF, H);

  ln_kernel<<<S, 256, 0, stream>>>(x, ln1w, ln1b, H1);

  gemm_kernel<0><<<dim3(S / 128, H / 128), 256, 0, stream>>>(H1, WT_Q, bq, nullptr, Qb, nullptr, S, H, H, 0.125f);
  gemm_kernel<0><<<dim3(S / 128, H / 128), 256, 0, stream>>>(H1, WT_K, bk, nullptr, Kbuf, nullptr, S, H, H, 1.0f);
  gemm_kernel<0><<<dim3(S / 128, H / 128), 256, 0, stream>>>(H1, WT_V, bv, nullptr, Vbuf, nullptr, S, H, H, 1.0f);

  attn_kernel<<<dim3(S / 64, NH), 256, 0, stream>>>(Qb, Kbuf, Vbuf, CTX);

  gemm_kernel<2><<<dim3(S / 128, H / 128), 256, 0, stream>>>(CTX, WT_O, bo, x, nullptr, X1, S, H, H, 1.0f);

  ln_kernel<<<S, 256, 0, stream>>>(X1, ln2w, ln2b, H2);

  gemm_kernel<1><<<dim3(S / 128, DFF / 128), 256, 0, stream>>>(H2, WT_1, b1, nullptr, MID, nullptr, S, DFF, H, 1.0f);
  gemm_kernel<2><<<dim3(S / 128, H / 128), 256, 0, stream>>>(MID, WT_2, b2, X1, nullptr, out, S, H, DFF, 1.0f);
}

// Round 3
// 635.735 us; speedup vs baseline: 1.2269x; 1.2269x over previous
//
#include <hip/hip_runtime.h>
#include <math.h>

#define H 2048
#define S 2048
#define NH 32
#define HD 64
#define DFF 8192

typedef __attribute__((ext_vector_type(4))) float f32x4;
typedef __attribute__((ext_vector_type(8))) short short8;

static __device__ __forceinline__ ushort f2bf(float f) {
  unsigned u = __float_as_uint(f);
  u += 0x7fff + ((u >> 16) & 1);
  return (ushort)(u >> 16);
}

static __device__ __forceinline__ void gl_lds16(const ushort* g, ushort* l) {
  __builtin_amdgcn_global_load_lds(
      (__attribute__((address_space(1))) const void*)g,
      (__attribute__((address_space(3))) void*)l, 16, 0, 0);
}

// transpose + cast fp32 -> bf16. W: [K][N] fp32; Wt: [N][K] bf16
__global__ __launch_bounds__(256) void transpose_cast_kernel(
    const float* __restrict__ W, ushort* __restrict__ Wt, int K, int N) {
  __shared__ ushort tile[32][33];
  int n0 = blockIdx.x * 32, k0 = blockIdx.y * 32;
  int tx = threadIdx.x & 31, ty = threadIdx.x >> 5;
#pragma unroll
  for (int i = 0; i < 4; i++) {
    int k = ty * 4 + i;
    tile[k][tx] = f2bf(W[(size_t)(k0 + k) * N + n0 + tx]);
  }
  __syncthreads();
#pragma unroll
  for (int i = 0; i < 4; i++) {
    int n = ty * 4 + i;
    Wt[(size_t)(n0 + n) * K + k0 + tx] = tile[tx][n];
  }
}

// bf16 transpose [S][H] -> [H][S]
__global__ __launch_bounds__(256) void vtrans_kernel(
    const ushort* __restrict__ V, ushort* __restrict__ VT) {
  __shared__ ushort tile[32][33];
  int s0 = blockIdx.x * 32, d0 = blockIdx.y * 32;
  int tx = threadIdx.x & 31, ty = threadIdx.x >> 5;
#pragma unroll
  for (int i = 0; i < 4; i++)
    tile[ty * 4 + i][tx] = V[(size_t)(s0 + ty * 4 + i) * H + d0 + tx];
  __syncthreads();
#pragma unroll
  for (int i = 0; i < 4; i++)
    VT[(size_t)(d0 + ty * 4 + i) * S + s0 + tx] = tile[tx][ty * 4 + i];
}

// concat bq|bk|bv into one 6144-float vector
__global__ __launch_bounds__(256) void biascat_kernel(
    const float* __restrict__ bq, const float* __restrict__ bk,
    const float* __restrict__ bv, float* __restrict__ o) {
  int t = blockIdx.x * 256 + threadIdx.x;
  o[t] = (t < H) ? bq[t] : (t < 2 * H) ? bk[t - H] : bv[t - 2 * H];
}

// LayerNorm fp32 -> bf16
__global__ __launch_bounds__(256) void ln_kernel(
    const float* __restrict__ x, const float* __restrict__ w,
    const float* __restrict__ b, ushort* __restrict__ out) {
  int row = blockIdx.x, t = threadIdx.x;
  const float4* xr = reinterpret_cast<const float4*>(x + (size_t)row * H);
  float4 v0 = xr[t * 2], v1 = xr[t * 2 + 1];
  float s = v0.x + v0.y + v0.z + v0.w + v1.x + v1.y + v1.z + v1.w;
  float q = v0.x * v0.x + v0.y * v0.y + v0.z * v0.z + v0.w * v0.w +
            v1.x * v1.x + v1.y * v1.y + v1.z * v1.z + v1.w * v1.w;
#pragma unroll
  for (int off = 32; off > 0; off >>= 1) {
    s += __shfl_down(s, off, 64);
    q += __shfl_down(q, off, 64);
  }
  __shared__ float sm[8];
  int lane = t & 63, wv = t >> 6;
  if (lane == 0) { sm[wv] = s; sm[wv + 4] = q; }
  __syncthreads();
  s = sm[0] + sm[1] + sm[2] + sm[3];
  q = sm[4] + sm[5] + sm[6] + sm[7];
  float mu = s * (1.0f / H);
  float var = q * (1.0f / H) - mu * mu;
  float rs = rsqrtf(var + 1e-5f);
  const float4* wr = reinterpret_cast<const float4*>(w);
  const float4* br = reinterpret_cast<const float4*>(b);
  float4 w0 = wr[t * 2], w1v = wr[t * 2 + 1], b0 = br[t * 2], b1v = br[t * 2 + 1];
  short8 pk;
  pk[0] = (short)f2bf((v0.x - mu) * rs * w0.x + b0.x);
  pk[1] = (short)f2bf((v0.y - mu) * rs * w0.y + b0.y);
  pk[2] = (short)f2bf((v0.z - mu) * rs * w0.z + b0.z);
  pk[3] = (short)f2bf((v0.w - mu) * rs * w0.w + b0.w);
  pk[4] = (short)f2bf((v1.x - mu) * rs * w1v.x + b1v.x);
  pk[5] = (short)f2bf((v1.y - mu) * rs * w1v.y + b1v.y);
  pk[6] = (short)f2bf((v1.z - mu) * rs * w1v.z + b1v.z);
  pk[7] = (short)f2bf((v1.w - mu) * rs * w1v.w + b1v.w);
  *reinterpret_cast<short8*>(out + (size_t)row * H + t * 8) = pk;
}

// out = res + p0 + p1 + bias (fp32)
__global__ __launch_bounds__(256) void combine_kernel(
    const float* __restrict__ res, const float* __restrict__ p0,
    const float* __restrict__ p1, const float* __restrict__ bias,
    float* __restrict__ out) {
  size_t i = (size_t)blockIdx.x * 256 + threadIdx.x;
  float4 a = reinterpret_cast<const float4*>(res)[i];
  float4 c0 = reinterpret_cast<const float4*>(p0)[i];
  float4 c1 = reinterpret_cast<const float4*>(p1)[i];
  int col = (int)((i * 4) & (H - 1));
  float4 bb = *reinterpret_cast<const float4*>(bias + col);
  float4 o;
  o.x = a.x + c0.x + c1.x + bb.x;
  o.y = a.y + c0.y + c1.y + bb.y;
  o.z = a.z + c0.z + c1.z + bb.z;
  o.w = a.w + c0.w + c1.w + bb.w;
  reinterpret_cast<float4*>(out)[i] = o;
}

// bf16 MFMA GEMM (global_load_lds staged), C = A[M,lda] @ Bt[N,lda]^T
// MODE 0: QKV split write to outb[(col>>11)*S*H + row*H + (col&2047)], Q cols scaled
// MODE 1: outb = bf16(gelu(acc+bias)) row-major [M][N]
// MODE 3: outf[z*M*N + row*N + col] = acc (raw fp32 partial, split-K)
template <int MODE>
__global__ __launch_bounds__(256) void gemm_kernel(
    const ushort* __restrict__ A, const ushort* __restrict__ Bt,
    const float* __restrict__ bias,
    ushort* __restrict__ outb, float* __restrict__ outf,
    int M, int N, int lda, int kbeg, int klen) {
  __shared__ __align__(16) ushort As[128 * 32];
  __shared__ __align__(16) ushort Bs[128 * 32];
  int tid = threadIdx.x;
  int lane = tid & 63, wave = tid >> 6;
  int m0 = blockIdx.x * 128, n0 = blockIdx.y * 128;
  int wm = (wave >> 1) * 64, wn = (wave & 1) * 64;
  int lm = lane & 15, kg = lane >> 4;
  int kb0 = kbeg + blockIdx.z * klen;

  f32x4 acc[4][4] = {};

  int srow = lane >> 2;
  int scol = (lane & 3) * 8;
  const ushort* ga0 = A + (size_t)(m0 + wave * 32 + srow) * lda + kb0 + scol;
  const ushort* ga1 = A + (size_t)(m0 + wave * 32 + 16 + srow) * lda + kb0 + scol;
  const ushort* gb0 = Bt + (size_t)(n0 + wave * 32 + srow) * lda + kb0 + scol;
  const ushort* gb1 = Bt + (size_t)(n0 + wave * 32 + 16 + srow) * lda + kb0 + scol;
  ushort* lA0 = As + wave * 1024;
  ushort* lA1 = lA0 + 512;
  ushort* lB0 = Bs + wave * 1024;
  ushort* lB1 = lB0 + 512;

  for (int k0 = 0; k0 < klen; k0 += 32) {
    __syncthreads();
    gl_lds16(ga0 + k0, lA0);
    gl_lds16(ga1 + k0, lA1);
    gl_lds16(gb0 + k0, lB0);
    gl_lds16(gb1 + k0, lB1);
    __syncthreads();
    short8 af[4], bfr[4];
#pragma unroll
    for (int i = 0; i < 4; i++)
      af[i] = *reinterpret_cast<const short8*>(&As[(wm + i * 16 + lm) * 32 + kg * 8]);
#pragma unroll
    for (int j = 0; j < 4; j++)
      bfr[j] = *reinterpret_cast<const short8*>(&Bs[(wn + j * 16 + lm) * 32 + kg * 8]);
#pragma unroll
    for (int i = 0; i < 4; i++)
#pragma unroll
      for (int j = 0; j < 4; j++)
        acc[i][j] = __builtin_amdgcn_mfma_f32_16x16x32_bf16(af[i], bfr[j], acc[i][j], 0, 0, 0);
  }

#pragma unroll
  for (int i = 0; i < 4; i++) {
#pragma unroll
    for (int j = 0; j < 4; j++) {
#pragma unroll
      for (int r = 0; r < 4; r++) {
        int row = m0 + wm + i * 16 + kg * 4 + r;
        int col = n0 + wn + j * 16 + lm;
        float v = acc[i][j][r];
        if (MODE == 0) {
          float t = v + bias[col];
          float sc = (col < H) ? 0.125f : 1.0f;
          size_t idx = (size_t)(col >> 11) * ((size_t)S * H) + (size_t)row * H + (col & (H - 1));
          outb[idx] = f2bf(t * sc);
        } else if (MODE == 1) {
          float t = v + bias[col];
          outb[(size_t)row * N + col] = f2bf(0.5f * t * (1.0f + erff(t * 0.70710678118f)));
        } else {
          outf[(size_t)blockIdx.z * M * N + (size_t)row * N + col] = v;
        }
      }
    }
  }
}

// causal flash attention, QBLK=128, KVB=64. Q pre-scaled. VT: [H][S]. ctx: [S,H].
__global__ __launch_bounds__(256) void attn_kernel(
    const ushort* __restrict__ Q, const ushort* __restrict__ Kmat,
    const ushort* __restrict__ VT, ushort* __restrict__ ctx) {
  __shared__ __align__(16) ushort Ks[64 * 64];
  __shared__ __align__(16) ushort Vs[64 * 64];
  __shared__ __align__(16) ushort Ps[4 * 32 * 64];
  int qbi = gridDim.x - 1 - blockIdx.x;  // big blocks first for causal balance
  int qbase = qbi * 128;
  int h = blockIdx.y;
  int tid = threadIdx.x, lane = tid & 63, w = tid >> 6;
  int lm = lane & 15, kg = lane >> 4;

  short8 qa[2][2];
#pragma unroll
  for (int qt = 0; qt < 2; qt++)
#pragma unroll
    for (int ks = 0; ks < 2; ks++)
      qa[qt][ks] = *reinterpret_cast<const short8*>(
          Q + (size_t)(qbase + qt * 64 + w * 16 + lm) * H + h * 64 + ks * 32 + kg * 8);

  float m_run[2][4], l_run[2][4];
  f32x4 o_acc[2][4] = {};
#pragma unroll
  for (int qt = 0; qt < 2; qt++)
#pragma unroll
    for (int r = 0; r < 4; r++) { m_run[qt][r] = -1e30f; l_run[qt][r] = 0.f; }

  int srow = lane >> 3;
  int sg = (lane & 7) ^ srow;  // pre-swizzled source granule
  int rk0 = w * 16 + srow, rk1 = rk0 + 8;
  ushort* lk0 = Ks + w * 1024;
  ushort* lv0 = Vs + w * 1024;

  int nkb = 2 * qbi + 2;
  for (int kb = 0; kb < nkb; kb++) {
    __syncthreads();
    gl_lds16(Kmat + (size_t)(kb * 64 + rk0) * H + h * 64 + sg * 8, lk0);
    gl_lds16(Kmat + (size_t)(kb * 64 + rk1) * H + h * 64 + sg * 8, lk0 + 512);
    gl_lds16(VT + (size_t)(h * 64 + rk0) * S + kb * 64 + sg * 8, lv0);
    gl_lds16(VT + (size_t)(h * 64 + rk1) * S + kb * 64 + sg * 8, lv0 + 512);
    __syncthreads();

    bool do0 = (kb <= 2 * qbi);

    f32x4 sacc[2][4] = {};
#pragma unroll
    for (int j = 0; j < 4; j++) {
      int krow = j * 16 + lm;
#pragma unroll
      for (int ks = 0; ks < 2; ks++) {
        short8 kf = *reinterpret_cast<const short8*>(
            &Ks[krow * 64 + (((ks * 4 + kg) ^ (lm & 7)) << 3)]);
        sacc[0][j] = __builtin_amdgcn_mfma_f32_16x16x32_bf16(qa[0][ks], kf, sacc[0][j], 0, 0, 0);
        sacc[1][j] = __builtin_amdgcn_mfma_f32_16x16x32_bf16(qa[1][ks], kf, sacc[1][j], 0, 0, 0);
      }
    }
    if (kb == 2 * qbi) {
#pragma unroll
      for (int j = 0; j < 4; j++)
#pragma unroll
        for (int r = 0; r < 4; r++)
          if (j * 16 + lm > w * 16 + kg * 4 + r) sacc[0][j][r] = -1e30f;
    }
    if (kb == 2 * qbi + 1) {
#pragma unroll
      for (int j = 0; j < 4; j++)
#pragma unroll
        for (int r = 0; r < 4; r++)
          if (j * 16 + lm > w * 16 + kg * 4 + r) sacc[1][j][r] = -1e30f;
    }

#pragma unroll
    for (int qt = 0; qt < 2; qt++) {
      if (qt == 0 && !do0) continue;
#pragma unroll
      for (int r = 0; r < 4; r++) {
        float t = fmaxf(fmaxf(sacc[qt][0][r], sacc[qt][1][r]),
                        fmaxf(sacc[qt][2][r], sacc[qt][3][r]));
        t = fmaxf(t, __shfl_xor(t, 1, 64));
        t = fmaxf(t, __shfl_xor(t, 2, 64));
        t = fmaxf(t, __shfl_xor(t, 4, 64));
        t = fmaxf(t, __shfl_xor(t, 8, 64));
        float mnew = fmaxf(m_run[qt][r], t);
        float sc = expf(m_run[qt][r] - mnew);
        m_run[qt][r] = mnew;
        float ps = 0.f;
#pragma unroll
        for (int j = 0; j < 4; j++) {
          float p = expf(sacc[qt][j][r] - mnew);
          sacc[qt][j][r] = p;
          ps += p;
        }
        ps += __shfl_xor(ps, 1, 64);
        ps += __shfl_xor(ps, 2, 64);
        ps += __shfl_xor(ps, 4, 64);
        ps += __shfl_xor(ps, 8, 64);
        l_run[qt][r] = l_run[qt][r] * sc + ps;
#pragma unroll
        for (int jd = 0; jd < 4; jd++) o_acc[qt][jd][r] *= sc;
      }
      // write P swizzled into this wave's private Ps region (intra-wave RAW only)
#pragma unroll
      for (int j = 0; j < 4; j++)
#pragma unroll
        for (int r = 0; r < 4; r++) {
          int rl = qt * 16 + kg * 4 + r;
          int col = j * 16 + lm;
          Ps[w * 2048 + rl * 64 + (((col >> 3) ^ (rl & 7)) << 3) + (col & 7)] =
              f2bf(sacc[qt][j][r]);
        }
    }

    short8 pa[2][2];
#pragma unroll
    for (int qt = 0; qt < 2; qt++)
#pragma unroll
      for (int ks = 0; ks < 2; ks++)
        pa[qt][ks] = *reinterpret_cast<const short8*>(
            &Ps[w * 2048 + (qt * 16 + lm) * 64 + (((ks * 4 + kg) ^ (lm & 7)) << 3)]);
#pragma unroll
    for (int jd = 0; jd < 4; jd++) {
      int vrow = jd * 16 + lm;
      short8 vf0 = *reinterpret_cast<const short8*>(&Vs[vrow * 64 + ((kg ^ (lm & 7)) << 3)]);
      short8 vf1 = *reinterpret_cast<const short8*>(&Vs[vrow * 64 + (((4 + kg) ^ (lm & 7)) << 3)]);
      if (do0) {
        o_acc[0][jd] = __builtin_amdgcn_mfma_f32_16x16x32_bf16(pa[0][0], vf0, o_acc[0][jd], 0, 0, 0);
        o_acc[0][jd] = __builtin_amdgcn_mfma_f32_16x16x32_bf16(pa[0][1], vf1, o_acc[0][jd], 0, 0, 0);
      }
      o_acc[1][jd] = __builtin_amdgcn_mfma_f32_16x16x32_bf16(pa[1][0], vf0, o_acc[1][jd], 0, 0, 0);
      o_acc[1][jd] = __builtin_amdgcn_mfma_f32_16x16x32_bf16(pa[1][1], vf1, o_acc[1][jd], 0, 0, 0);
    }
  }

#pragma unroll
  for (int qt = 0; qt < 2; qt++)
#pragma unroll
    for (int jd = 0; jd < 4; jd++)
#pragma unroll
      for (int r = 0; r < 4; r++) {
        int row = qbase + qt * 64 + w * 16 + kg * 4 + r;
        int col = h * 64 + jd * 16 + lm;
        ctx[(size_t)row * H + col] = f2bf(o_acc[qt][jd][r] / l_run[qt][r]);
      }
}

extern "C" void kernel_launch(void* const* d_in, const int* in_sizes, int n_in,
                              void* d_out, int out_size, void* d_ws, size_t ws_size,
                              hipStream_t stream) {
  const float* x = (const float*)d_in[0];
  const float* ln1w = (const float*)d_in[2];
  const float* ln1b = (const float*)d_in[3];
  const float* wq = (const float*)d_in[4];
  const float* bq = (const float*)d_in[5];
  const float* wk = (const float*)d_in[6];
  const float* bk = (const float*)d_in[7];
  const float* wv = (const float*)d_in[8];
  const float* bv = (const float*)d_in[9];
  const float* wo = (const float*)d_in[10];
  const float* bo = (const float*)d_in[11];
  const float* w1 = (const float*)d_in[12];
  const float* b1 = (const float*)d_in[13];
  const float* w2 = (const float*)d_in[14];
  const float* b2 = (const float*)d_in[15];
  const float* ln2w = (const float*)d_in[16];
  const float* ln2b = (const float*)d_in[17];
  float* out = (float*)d_out;

  char* ws = (char*)d_ws;
  const size_t MB = 1024 * 1024;
  const size_t SH = (size_t)S * H;
  ushort* WT_QKV = (ushort*)(ws);
  ushort* WT_O = (ushort*)(ws + 24 * MB);
  ushort* WT_1 = (ushort*)(ws + 32 * MB);
  ushort* WT_2 = (ushort*)(ws + 64 * MB);
  ushort* LNO = (ushort*)(ws + 96 * MB);
  ushort* QKVB = (ushort*)(ws + 104 * MB);
  ushort* VTb = (ushort*)(ws + 128 * MB);
  ushort* CTX = (ushort*)(ws + 136 * MB);
  float* X1 = (float*)(ws + 144 * MB);
  float* BIASQ = (float*)(ws + 160 * MB);
  ushort* MID = (ushort*)(ws);
  float* SP = (float*)(ws + 104 * MB);

  transpose_cast_kernel<<<dim3(H / 32, H / 32), 256, 0, stream>>>(wq, WT_QKV, H, H);
  transpose_cast_kernel<<<dim3(H / 32, H / 32), 256, 0, stream>>>(wk, WT_QKV + SH, H, H);
  transpose_cast_kernel<<<dim3(H / 32, H / 32), 256, 0, stream>>>(wv, WT_QKV + 2 * SH, H, H);
  transpose_cast_kernel<<<dim3(H / 32, H / 32), 256, 0, stream>>>(wo, WT_O, H, H);
  transpose_cast_kernel<<<dim3(DFF / 32, H / 32), 256, 0, stream>>>(w1, WT_1, H, DFF);
  transpose_cast_kernel<<<dim3(H / 32, DFF / 32), 256, 0, stream>>>(w2, WT_2, DFF, H);
  biascat_kernel<<<3 * H / 256, 256, 0, stream>>>(bq, bk, bv, BIASQ);

  ln_kernel<<<S, 256, 0, stream>>>(x, ln1w, ln1b, LNO);

  gemm_kernel<0><<<dim3(S / 128, 3 * H / 128), 256, 0, stream>>>(
      LNO, WT_QKV, BIASQ, QKVB, nullptr, S, 3 * H, H, 0, H);

  vtrans_kernel<<<dim3(S / 32, H / 32), 256, 0, stream>>>(QKVB + 2 * SH, VTb);

  attn_kernel<<<dim3(S / 128, NH), 256, 0, stream>>>(QKVB, QKVB + SH, VTb, CTX);

  gemm_kernel<3><<<dim3(S / 128, H / 128, 2), 256, 0, stream>>>(
      CTX, WT_O, nullptr, nullptr, SP, S, H, H, 0, H / 2);
  combine_kernel<<<SH / 1024, 256, 0, stream>>>(x, SP, SP + SH, bo, X1);

  ln_kernel<<<S, 256, 0, stream>>>(X1, ln2w, ln2b, LNO);

  gemm_kernel<1><<<dim3(S / 128, DFF / 128), 256, 0, stream>>>(
      LNO, WT_1, b1, MID, nullptr, S, DFF, H, 0, H);

  gemm_kernel<3><<<dim3(S / 128, H / 128, 2), 256, 0, stream>>>(
      MID, WT_2, nullptr, nullptr, SP, S, H, DFF, 0, DFF / 2);
  combine_kernel<<<SH / 1024, 256, 0, stream>>>(X1, SP, SP + SH, b2, out);
}

// Round 4
// 608.266 us; speedup vs baseline: 1.2823x; 1.0452x over previous
//
#include <hip/hip_runtime.h>
#include <math.h>

#define H 2048
#define S 2048
#define NH 32
#define HD 64
#define DFF 8192

typedef __attribute__((ext_vector_type(4))) float f32x4;
typedef __attribute__((ext_vector_type(8))) short short8;

static __device__ __forceinline__ ushort f2bf(float f) {
  unsigned u = __float_as_uint(f);
  u += 0x7fff + ((u >> 16) & 1);
  return (ushort)(u >> 16);
}

static __device__ __forceinline__ void gl_lds16(const ushort* g, ushort* l) {
  __builtin_amdgcn_global_load_lds(
      (__attribute__((address_space(1))) const void*)g,
      (__attribute__((address_space(3))) void*)l, 16, 0, 0);
}

// transpose + cast fp32 -> bf16. W: [K][N] fp32; Wt: [N][K] bf16. 64x64 tiles.
__global__ __launch_bounds__(256) void transpose_cast_kernel(
    const float* __restrict__ W, ushort* __restrict__ Wt, int K, int N) {
  __shared__ __align__(16) ushort tile[64][72];  // row 144B (16B-mult), granule-XOR swizzle
  int n0 = blockIdx.x * 64, k0 = blockIdx.y * 64;
  int t = threadIdx.x;
  int lk = t >> 4;          // 0..15
  int ln4 = (t & 15) * 4;   // col group of 4
#pragma unroll
  for (int p = 0; p < 4; p++) {
    int k = p * 16 + lk;
    float4 v = *reinterpret_cast<const float4*>(&W[(size_t)(k0 + k) * N + n0 + ln4]);
    float vv[4] = {v.x, v.y, v.z, v.w};
#pragma unroll
    for (int i = 0; i < 4; i++) {
      int row = ln4 + i;
      int slot = ((k >> 3) ^ (row & 7));
      tile[row][(slot << 3) + (k & 7)] = f2bf(vv[i]);
    }
  }
  __syncthreads();
  int n = t >> 2;           // 0..63
  int kq = (t & 3) * 8;
#pragma unroll
  for (int p = 0; p < 2; p++) {
    int kk = kq + p * 32;
    int slot = ((kk >> 3) ^ (n & 7));
    short8 o = *reinterpret_cast<const short8*>(&tile[n][slot << 3]);
    *reinterpret_cast<short8*>(&Wt[(size_t)(n0 + n) * K + k0 + kk]) = o;
  }
}

// bf16 transpose [S][H] -> [H][S]
__global__ __launch_bounds__(256) void vtrans_kernel(
    const ushort* __restrict__ V, ushort* __restrict__ VT) {
  __shared__ ushort tile[32][33];
  int s0 = blockIdx.x * 32, d0 = blockIdx.y * 32;
  int tx = threadIdx.x & 31, ty = threadIdx.x >> 5;
#pragma unroll
  for (int i = 0; i < 4; i++)
    tile[ty * 4 + i][tx] = V[(size_t)(s0 + ty * 4 + i) * H + d0 + tx];
  __syncthreads();
#pragma unroll
  for (int i = 0; i < 4; i++)
    VT[(size_t)(d0 + ty * 4 + i) * S + s0 + tx] = tile[tx][ty * 4 + i];
}

// concat bq|bk|bv into one 6144-float vector
__global__ __launch_bounds__(256) void biascat_kernel(
    const float* __restrict__ bq, const float* __restrict__ bk,
    const float* __restrict__ bv, float* __restrict__ o) {
  int t = blockIdx.x * 256 + threadIdx.x;
  o[t] = (t < H) ? bq[t] : (t < 2 * H) ? bk[t - H] : bv[t - 2 * H];
}

// LayerNorm fp32 -> bf16
__global__ __launch_bounds__(256) void ln_kernel(
    const float* __restrict__ x, const float* __restrict__ w,
    const float* __restrict__ b, ushort* __restrict__ out) {
  int row = blockIdx.x, t = threadIdx.x;
  const float4* xr = reinterpret_cast<const float4*>(x + (size_t)row * H);
  float4 v0 = xr[t * 2], v1 = xr[t * 2 + 1];
  float s = v0.x + v0.y + v0.z + v0.w + v1.x + v1.y + v1.z + v1.w;
  float q = v0.x * v0.x + v0.y * v0.y + v0.z * v0.z + v0.w * v0.w +
            v1.x * v1.x + v1.y * v1.y + v1.z * v1.z + v1.w * v1.w;
#pragma unroll
  for (int off = 32; off > 0; off >>= 1) {
    s += __shfl_down(s, off, 64);
    q += __shfl_down(q, off, 64);
  }
  __shared__ float sm[8];
  int lane = t & 63, wv = t >> 6;
  if (lane == 0) { sm[wv] = s; sm[wv + 4] = q; }
  __syncthreads();
  s = sm[0] + sm[1] + sm[2] + sm[3];
  q = sm[4] + sm[5] + sm[6] + sm[7];
  float mu = s * (1.0f / H);
  float var = q * (1.0f / H) - mu * mu;
  float rs = rsqrtf(var + 1e-5f);
  const float4* wr = reinterpret_cast<const float4*>(w);
  const float4* br = reinterpret_cast<const float4*>(b);
  float4 w0 = wr[t * 2], w1v = wr[t * 2 + 1], b0 = br[t * 2], b1v = br[t * 2 + 1];
  short8 pk;
  pk[0] = (short)f2bf((v0.x - mu) * rs * w0.x + b0.x);
  pk[1] = (short)f2bf((v0.y - mu) * rs * w0.y + b0.y);
  pk[2] = (short)f2bf((v0.z - mu) * rs * w0.z + b0.z);
  pk[3] = (short)f2bf((v0.w - mu) * rs * w0.w + b0.w);
  pk[4] = (short)f2bf((v1.x - mu) * rs * w1v.x + b1v.x);
  pk[5] = (short)f2bf((v1.y - mu) * rs * w1v.y + b1v.y);
  pk[6] = (short)f2bf((v1.z - mu) * rs * w1v.z + b1v.z);
  pk[7] = (short)f2bf((v1.w - mu) * rs * w1v.w + b1v.w);
  *reinterpret_cast<short8*>(out + (size_t)row * H + t * 8) = pk;
}

// out = res + p0 + p1 + bias (fp32)
__global__ __launch_bounds__(256) void combine_kernel(
    const float* __restrict__ res, const float* __restrict__ p0,
    const float* __restrict__ p1, const float* __restrict__ bias,
    float* __restrict__ out) {
  size_t i = (size_t)blockIdx.x * 256 + threadIdx.x;
  float4 a = reinterpret_cast<const float4*>(res)[i];
  float4 c0 = reinterpret_cast<const float4*>(p0)[i];
  float4 c1 = reinterpret_cast<const float4*>(p1)[i];
  int col = (int)((i * 4) & (H - 1));
  float4 bb = *reinterpret_cast<const float4*>(bias + col);
  float4 o;
  o.x = a.x + c0.x + c1.x + bb.x;
  o.y = a.y + c0.y + c1.y + bb.y;
  o.z = a.z + c0.z + c1.z + bb.z;
  o.w = a.w + c0.w + c1.w + bb.w;
  reinterpret_cast<float4*>(out)[i] = o;
}

// bf16 MFMA GEMM, 2-phase prefetch + XCD swizzle. C = A[M,lda] @ Bt[N,lda]^T
// MODE 0: QKV split write to outb[(col>>11)*S*H + row*H + (col&2047)], Q cols scaled
// MODE 1: outb = bf16(gelu(acc+bias)) row-major [M][N]
// MODE 3: outf[z*M*N + row*N + col] = acc (raw fp32 partial, split-K)
template <int MODE>
__global__ __launch_bounds__(256) void gemm_kernel(
    const ushort* __restrict__ A, const ushort* __restrict__ Bt,
    const float* __restrict__ bias,
    ushort* __restrict__ outb, float* __restrict__ outf,
    int M, int N, int lda, int kbeg, int klen) {
  __shared__ __align__(16) ushort As[2][128 * 32];
  __shared__ __align__(16) ushort Bs[2][128 * 32];
  int tid = threadIdx.x;
  int lane = tid & 63, wave = tid >> 6;
  // bijective XCD swizzle (all launches have nwg % 8 == 0)
  int gx = gridDim.x, nwg = gx * gridDim.y;
  int orig = blockIdx.y * gx + blockIdx.x;
  int wg = (orig & 7) * (nwg >> 3) + (orig >> 3);
  int m0 = (wg % gx) * 128, n0 = (wg / gx) * 128;
  int wm = (wave >> 1) * 64, wn = (wave & 1) * 64;
  int lm = lane & 15, kg = lane >> 4;
  int kb0 = kbeg + blockIdx.z * klen;

  f32x4 acc[4][4] = {};

  int srow = lane >> 2;
  int scol = (lane & 3) * 8;
  const ushort* ga0 = A + (size_t)(m0 + wave * 32 + srow) * lda + kb0 + scol;
  const ushort* ga1 = A + (size_t)(m0 + wave * 32 + 16 + srow) * lda + kb0 + scol;
  const ushort* gb0 = Bt + (size_t)(n0 + wave * 32 + srow) * lda + kb0 + scol;
  const ushort* gb1 = Bt + (size_t)(n0 + wave * 32 + 16 + srow) * lda + kb0 + scol;

  // prologue: stage k-step 0 into buf 0
  gl_lds16(ga0, &As[0][wave * 1024]);
  gl_lds16(ga1, &As[0][wave * 1024 + 512]);
  gl_lds16(gb0, &Bs[0][wave * 1024]);
  gl_lds16(gb1, &Bs[0][wave * 1024 + 512]);
  __syncthreads();

  for (int k0 = 0; k0 < klen; k0 += 32) {
    int cur = (k0 >> 5) & 1;
    int nxt = cur ^ 1;
    if (k0 + 32 < klen) {
      gl_lds16(ga0 + k0 + 32, &As[nxt][wave * 1024]);
      gl_lds16(ga1 + k0 + 32, &As[nxt][wave * 1024 + 512]);
      gl_lds16(gb0 + k0 + 32, &Bs[nxt][wave * 1024]);
      gl_lds16(gb1 + k0 + 32, &Bs[nxt][wave * 1024 + 512]);
    }
    short8 af[4], bfr[4];
#pragma unroll
    for (int i = 0; i < 4; i++)
      af[i] = *reinterpret_cast<const short8*>(&As[cur][(wm + i * 16 + lm) * 32 + kg * 8]);
#pragma unroll
    for (int j = 0; j < 4; j++)
      bfr[j] = *reinterpret_cast<const short8*>(&Bs[cur][(wn + j * 16 + lm) * 32 + kg * 8]);
#pragma unroll
    for (int i = 0; i < 4; i++)
#pragma unroll
      for (int j = 0; j < 4; j++)
        acc[i][j] = __builtin_amdgcn_mfma_f32_16x16x32_bf16(af[i], bfr[j], acc[i][j], 0, 0, 0);
    __syncthreads();
  }

#pragma unroll
  for (int i = 0; i < 4; i++) {
#pragma unroll
    for (int j = 0; j < 4; j++) {
#pragma unroll
      for (int r = 0; r < 4; r++) {
        int row = m0 + wm + i * 16 + kg * 4 + r;
        int col = n0 + wn + j * 16 + lm;
        float v = acc[i][j][r];
        if (MODE == 0) {
          float t = v + bias[col];
          float sc = (col < H) ? 0.125f : 1.0f;
          size_t idx = (size_t)(col >> 11) * ((size_t)S * H) + (size_t)row * H + (col & (H - 1));
          outb[idx] = f2bf(t * sc);
        } else if (MODE == 1) {
          float t = v + bias[col];
          outb[(size_t)row * N + col] = f2bf(0.5f * t * (1.0f + erff(t * 0.70710678118f)));
        } else {
          outf[(size_t)blockIdx.z * M * N + (size_t)row * N + col] = v;
        }
      }
    }
  }
}

// causal flash attention, QBLK=128, KVB=128, K/V double-buffered.
// Q pre-scaled. VT: [H][S]. ctx: [S,H].
__global__ __launch_bounds__(256) void attn_kernel(
    const ushort* __restrict__ Q, const ushort* __restrict__ Kmat,
    const ushort* __restrict__ VT, ushort* __restrict__ ctx) {
  __shared__ __align__(16) ushort Ks[2][128 * 64];  // 2 x 16KB, [key][d] XOR-swizzled
  __shared__ __align__(16) ushort Vs[2][64 * 128];  // 2 x 16KB, [d][key] XOR-swizzled
  __shared__ __align__(16) ushort Ps[4 * 32 * 64];  // 16KB, per-wave
  int qbi = gridDim.x - 1 - blockIdx.x;  // big blocks first for causal balance
  int qbase = qbi * 128;
  int h = blockIdx.y;
  int tid = threadIdx.x, lane = tid & 63, w = tid >> 6;
  int lm = lane & 15, kg = lane >> 4;

  short8 qa[2][2];
#pragma unroll
  for (int qt = 0; qt < 2; qt++)
#pragma unroll
    for (int ks = 0; ks < 2; ks++)
      qa[qt][ks] = *reinterpret_cast<const short8*>(
          Q + (size_t)(qbase + qt * 64 + w * 16 + lm) * H + h * 64 + ks * 32 + kg * 8);

  float m_run[2][4], l_run[2][4];
  f32x4 o_acc[2][4] = {};
#pragma unroll
  for (int qt = 0; qt < 2; qt++)
#pragma unroll
    for (int r = 0; r < 4; r++) { m_run[qt][r] = -1e30f; l_run[qt][r] = 0.f; }

  int nkb = qbi + 1;

  // staging: K tile = 128 rows x 64 d (8 granules/row), V tile = 64 rows x 128 keys (16/row)
  auto stage = [&](int kb, int buf) {
#pragma unroll
    for (int p = 0; p < 4; p++) {
      int gbase = p * 256 + w * 64;          // uniform per wave
      int gran = gbase + lane;               // per-lane (source only)
      int krow = gran >> 3, gk = gran & 7;
      gl_lds16(Kmat + (size_t)(kb * 128 + krow) * H + h * 64 + ((gk ^ (krow & 7)) << 3),
               &Ks[buf][gbase * 8]);
    }
#pragma unroll
    for (int p = 0; p < 4; p++) {
      int gbase = p * 256 + w * 64;
      int gran = gbase + lane;
      int vrow = gran >> 4, gv = gran & 15;
      gl_lds16(VT + (size_t)(h * 64 + vrow) * S + kb * 128 + ((gv ^ (vrow & 15)) << 3),
               &Vs[buf][gbase * 8]);
    }
  };

  stage(0, 0);
  __syncthreads();

  for (int kb = 0; kb < nkb; kb++) {
    int cur = kb & 1;
    if (kb + 1 < nkb) stage(kb + 1, cur ^ 1);

    // QK^T: 32 q-rows (this wave) x 128 keys
    f32x4 sacc[2][8] = {};
#pragma unroll
    for (int j = 0; j < 8; j++) {
      int krow = j * 16 + lm;
#pragma unroll
      for (int ks = 0; ks < 2; ks++) {
        short8 kf = *reinterpret_cast<const short8*>(
            &Ks[cur][krow * 64 + (((ks * 4 + kg) ^ (lm & 7)) << 3)]);
        sacc[0][j] = __builtin_amdgcn_mfma_f32_16x16x32_bf16(qa[0][ks], kf, sacc[0][j], 0, 0, 0);
        sacc[1][j] = __builtin_amdgcn_mfma_f32_16x16x32_bf16(qa[1][ks], kf, sacc[1][j], 0, 0, 0);
      }
    }
    if (kb == qbi) {
#pragma unroll
      for (int qt = 0; qt < 2; qt++)
#pragma unroll
        for (int j = 0; j < 8; j++)
#pragma unroll
          for (int r = 0; r < 4; r++)
            if (j * 16 + lm > qt * 64 + w * 16 + kg * 4 + r) sacc[qt][j][r] = -1e30f;
    }

    // online softmax
#pragma unroll
    for (int qt = 0; qt < 2; qt++) {
#pragma unroll
      for (int r = 0; r < 4; r++) {
        float mx = sacc[qt][0][r];
#pragma unroll
        for (int j = 1; j < 8; j++) mx = fmaxf(mx, sacc[qt][j][r]);
        mx = fmaxf(mx, __shfl_xor(mx, 1, 64));
        mx = fmaxf(mx, __shfl_xor(mx, 2, 64));
        mx = fmaxf(mx, __shfl_xor(mx, 4, 64));
        mx = fmaxf(mx, __shfl_xor(mx, 8, 64));
        float mnew = fmaxf(m_run[qt][r], mx);
        float sc = __expf(m_run[qt][r] - mnew);
        m_run[qt][r] = mnew;
        float ps = 0.f;
#pragma unroll
        for (int j = 0; j < 8; j++) {
          float p = __expf(sacc[qt][j][r] - mnew);
          sacc[qt][j][r] = p;
          ps += p;
        }
        ps += __shfl_xor(ps, 1, 64);
        ps += __shfl_xor(ps, 2, 64);
        ps += __shfl_xor(ps, 4, 64);
        ps += __shfl_xor(ps, 8, 64);
        l_run[qt][r] = l_run[qt][r] * sc + ps;
#pragma unroll
        for (int jd = 0; jd < 4; jd++) o_acc[qt][jd][r] *= sc;
      }
    }

    // PV in two 64-key chunks through per-wave Ps (in-order DS ops, no barrier)
#pragma unroll
    for (int c = 0; c < 2; c++) {
#pragma unroll
      for (int qt = 0; qt < 2; qt++)
#pragma unroll
        for (int jj = 0; jj < 4; jj++)
#pragma unroll
          for (int r = 0; r < 4; r++) {
            int rl = qt * 16 + kg * 4 + r;
            int col = jj * 16 + lm;
            Ps[w * 2048 + rl * 64 + (((col >> 3) ^ (rl & 7)) << 3) + (col & 7)] =
                f2bf(sacc[qt][c * 4 + jj][r]);
          }
      short8 pa0[2], pa1[2];
#pragma unroll
      for (int ks = 0; ks < 2; ks++) {
        pa0[ks] = *reinterpret_cast<const short8*>(
            &Ps[w * 2048 + lm * 64 + (((ks * 4 + kg) ^ (lm & 7)) << 3)]);
        pa1[ks] = *reinterpret_cast<const short8*>(
            &Ps[w * 2048 + (16 + lm) * 64 + (((ks * 4 + kg) ^ (lm & 7)) << 3)]);
      }
#pragma unroll
      for (int jd = 0; jd < 4; jd++) {
        int d = jd * 16 + lm;
#pragma unroll
        for (int ks = 0; ks < 2; ks++) {
          short8 vf = *reinterpret_cast<const short8*>(
              &Vs[cur][d * 128 + (((c * 8 + ks * 4 + kg) ^ lm) << 3)]);
          o_acc[0][jd] = __builtin_amdgcn_mfma_f32_16x16x32_bf16(pa0[ks], vf, o_acc[0][jd], 0, 0, 0);
          o_acc[1][jd] = __builtin_amdgcn_mfma_f32_16x16x32_bf16(pa1[ks], vf, o_acc[1][jd], 0, 0, 0);
        }
      }
    }
    __syncthreads();  // next-tile loads drained; buf reads done before re-stage
  }

#pragma unroll
  for (int qt = 0; qt < 2; qt++)
#pragma unroll
    for (int jd = 0; jd < 4; jd++)
#pragma unroll
      for (int r = 0; r < 4; r++) {
        int row = qbase + qt * 64 + w * 16 + kg * 4 + r;
        int col = h * 64 + jd * 16 + lm;
        ctx[(size_t)row * H + col] = f2bf(o_acc[qt][jd][r] / l_run[qt][r]);
      }
}

extern "C" void kernel_launch(void* const* d_in, const int* in_sizes, int n_in,
                              void* d_out, int out_size, void* d_ws, size_t ws_size,
                              hipStream_t stream) {
  const float* x = (const float*)d_in[0];
  const float* ln1w = (const float*)d_in[2];
  const float* ln1b = (const float*)d_in[3];
  const float* wq = (const float*)d_in[4];
  const float* bq = (const float*)d_in[5];
  const float* wk = (const float*)d_in[6];
  const float* bk = (const float*)d_in[7];
  const float* wv = (const float*)d_in[8];
  const float* bv = (const float*)d_in[9];
  const float* wo = (const float*)d_in[10];
  const float* bo = (const float*)d_in[11];
  const float* w1 = (const float*)d_in[12];
  const float* b1 = (const float*)d_in[13];
  const float* w2 = (const float*)d_in[14];
  const float* b2 = (const float*)d_in[15];
  const float* ln2w = (const float*)d_in[16];
  const float* ln2b = (const float*)d_in[17];
  float* out = (float*)d_out;

  char* ws = (char*)d_ws;
  const size_t MB = 1024 * 1024;
  const size_t SH = (size_t)S * H;
  ushort* WT_QKV = (ushort*)(ws);
  ushort* WT_O = (ushort*)(ws + 24 * MB);
  ushort* WT_1 = (ushort*)(ws + 32 * MB);
  ushort* WT_2 = (ushort*)(ws + 64 * MB);
  ushort* LNO = (ushort*)(ws + 96 * MB);
  ushort* QKVB = (ushort*)(ws + 104 * MB);
  ushort* VTb = (ushort*)(ws + 128 * MB);
  ushort* CTX = (ushort*)(ws + 136 * MB);
  float* X1 = (float*)(ws + 144 * MB);
  float* BIASQ = (float*)(ws + 160 * MB);
  ushort* MID = (ushort*)(ws);
  float* SP = (float*)(ws + 104 * MB);

  transpose_cast_kernel<<<dim3(H / 64, H / 64), 256, 0, stream>>>(wq, WT_QKV, H, H);
  transpose_cast_kernel<<<dim3(H / 64, H / 64), 256, 0, stream>>>(wk, WT_QKV + SH, H, H);
  transpose_cast_kernel<<<dim3(H / 64, H / 64), 256, 0, stream>>>(wv, WT_QKV + 2 * SH, H, H);
  transpose_cast_kernel<<<dim3(H / 64, H / 64), 256, 0, stream>>>(wo, WT_O, H, H);
  transpose_cast_kernel<<<dim3(DFF / 64, H / 64), 256, 0, stream>>>(w1, WT_1, H, DFF);
  transpose_cast_kernel<<<dim3(H / 64, DFF / 64), 256, 0, stream>>>(w2, WT_2, DFF, H);
  biascat_kernel<<<3 * H / 256, 256, 0, stream>>>(bq, bk, bv, BIASQ);

  ln_kernel<<<S, 256, 0, stream>>>(x, ln1w, ln1b, LNO);

  gemm_kernel<0><<<dim3(S / 128, 3 * H / 128), 256, 0, stream>>>(
      LNO, WT_QKV, BIASQ, QKVB, nullptr, S, 3 * H, H, 0, H);

  vtrans_kernel<<<dim3(S / 32, H / 32), 256, 0, stream>>>(QKVB + 2 * SH, VTb);

  attn_kernel<<<dim3(S / 128, NH), 256, 0, stream>>>(QKVB, QKVB + SH, VTb, CTX);

  gemm_kernel<3><<<dim3(S / 128, H / 128, 2), 256, 0, stream>>>(
      CTX, WT_O, nullptr, nullptr, SP, S, H, H, 0, H / 2);
  combine_kernel<<<SH / 1024, 256, 0, stream>>>(x, SP, SP + SH, bo, X1);

  ln_kernel<<<S, 256, 0, stream>>>(X1, ln2w, ln2b, LNO);

  gemm_kernel<1><<<dim3(S / 128, DFF / 128), 256, 0, stream>>>(
      LNO, WT_1, b1, MID, nullptr, S, DFF, H, 0, H);

  gemm_kernel<3><<<dim3(S / 128, H / 128, 2), 256, 0, stream>>>(
      MID, WT_2, nullptr, nullptr, SP, S, H, DFF, 0, DFF / 2);
  combine_kernel<<<SH / 1024, 256, 0, stream>>>(X1, SP, SP + SH, b2, out);
}

// Round 5
// 502.618 us; speedup vs baseline: 1.5518x; 1.2102x over previous
//
#include <hip/hip_runtime.h>
#include <math.h>

#define H 2048
#define S 2048
#define NH 32
#define HD 64
#define DFF 8192

typedef __attribute__((ext_vector_type(4))) float f32x4;
typedef __attribute__((ext_vector_type(8))) short short8;

static __device__ __forceinline__ ushort f2bf(float f) {
  unsigned u = __float_as_uint(f);
  u += 0x7fff + ((u >> 16) & 1);
  return (ushort)(u >> 16);
}

static __device__ __forceinline__ void gl_lds16(const ushort* g, ushort* l) {
  __builtin_amdgcn_global_load_lds(
      (__attribute__((address_space(1))) const void*)g,
      (__attribute__((address_space(3))) void*)l, 16, 0, 0);
}

// transpose + cast fp32 -> bf16. W: [K][N] fp32; Wt: [N][K] bf16. 64x64 tiles.
__global__ __launch_bounds__(256) void transpose_cast_kernel(
    const float* __restrict__ W, ushort* __restrict__ Wt, int K, int N) {
  __shared__ __align__(16) ushort tile[64][72];
  int n0 = blockIdx.x * 64, k0 = blockIdx.y * 64;
  int t = threadIdx.x;
  int lk = t >> 4;
  int ln4 = (t & 15) * 4;
#pragma unroll
  for (int p = 0; p < 4; p++) {
    int k = p * 16 + lk;
    float4 v = *reinterpret_cast<const float4*>(&W[(size_t)(k0 + k) * N + n0 + ln4]);
    float vv[4] = {v.x, v.y, v.z, v.w};
#pragma unroll
    for (int i = 0; i < 4; i++) {
      int row = ln4 + i;
      int slot = ((k >> 3) ^ (row & 7));
      tile[row][(slot << 3) + (k & 7)] = f2bf(vv[i]);
    }
  }
  __syncthreads();
  int n = t >> 2;
  int kq = (t & 3) * 8;
#pragma unroll
  for (int p = 0; p < 2; p++) {
    int kk = kq + p * 32;
    int slot = ((kk >> 3) ^ (n & 7));
    short8 o = *reinterpret_cast<const short8*>(&tile[n][slot << 3]);
    *reinterpret_cast<short8*>(&Wt[(size_t)(n0 + n) * K + k0 + kk]) = o;
  }
}

// bf16 transpose [S][H] -> [H][S]
__global__ __launch_bounds__(256) void vtrans_kernel(
    const ushort* __restrict__ V, ushort* __restrict__ VT) {
  __shared__ ushort tile[32][33];
  int s0 = blockIdx.x * 32, d0 = blockIdx.y * 32;
  int tx = threadIdx.x & 31, ty = threadIdx.x >> 5;
#pragma unroll
  for (int i = 0; i < 4; i++)
    tile[ty * 4 + i][tx] = V[(size_t)(s0 + ty * 4 + i) * H + d0 + tx];
  __syncthreads();
#pragma unroll
  for (int i = 0; i < 4; i++)
    VT[(size_t)(d0 + ty * 4 + i) * S + s0 + tx] = tile[tx][ty * 4 + i];
}

// concat bq|bk|bv into one 6144-float vector
__global__ __launch_bounds__(256) void biascat_kernel(
    const float* __restrict__ bq, const float* __restrict__ bk,
    const float* __restrict__ bv, float* __restrict__ o) {
  int t = blockIdx.x * 256 + threadIdx.x;
  o[t] = (t < H) ? bq[t] : (t < 2 * H) ? bk[t - H] : bv[t - 2 * H];
}

// LayerNorm fp32 -> bf16
__global__ __launch_bounds__(256) void ln_kernel(
    const float* __restrict__ x, const float* __restrict__ w,
    const float* __restrict__ b, ushort* __restrict__ out) {
  int row = blockIdx.x, t = threadIdx.x;
  const float4* xr = reinterpret_cast<const float4*>(x + (size_t)row * H);
  float4 v0 = xr[t * 2], v1 = xr[t * 2 + 1];
  float s = v0.x + v0.y + v0.z + v0.w + v1.x + v1.y + v1.z + v1.w;
  float q = v0.x * v0.x + v0.y * v0.y + v0.z * v0.z + v0.w * v0.w +
            v1.x * v1.x + v1.y * v1.y + v1.z * v1.z + v1.w * v1.w;
#pragma unroll
  for (int off = 32; off > 0; off >>= 1) {
    s += __shfl_down(s, off, 64);
    q += __shfl_down(q, off, 64);
  }
  __shared__ float sm[8];
  int lane = t & 63, wv = t >> 6;
  if (lane == 0) { sm[wv] = s; sm[wv + 4] = q; }
  __syncthreads();
  s = sm[0] + sm[1] + sm[2] + sm[3];
  q = sm[4] + sm[5] + sm[6] + sm[7];
  float mu = s * (1.0f / H);
  float var = q * (1.0f / H) - mu * mu;
  float rs = rsqrtf(var + 1e-5f);
  const float4* wr = reinterpret_cast<const float4*>(w);
  const float4* br = reinterpret_cast<const float4*>(b);
  float4 w0 = wr[t * 2], w1v = wr[t * 2 + 1], b0 = br[t * 2], b1v = br[t * 2 + 1];
  short8 pk;
  pk[0] = (short)f2bf((v0.x - mu) * rs * w0.x + b0.x);
  pk[1] = (short)f2bf((v0.y - mu) * rs * w0.y + b0.y);
  pk[2] = (short)f2bf((v0.z - mu) * rs * w0.z + b0.z);
  pk[3] = (short)f2bf((v0.w - mu) * rs * w0.w + b0.w);
  pk[4] = (short)f2bf((v1.x - mu) * rs * w1v.x + b1v.x);
  pk[5] = (short)f2bf((v1.y - mu) * rs * w1v.y + b1v.y);
  pk[6] = (short)f2bf((v1.z - mu) * rs * w1v.z + b1v.z);
  pk[7] = (short)f2bf((v1.w - mu) * rs * w1v.w + b1v.w);
  *reinterpret_cast<short8*>(out + (size_t)row * H + t * 8) = pk;
}

// out = res + p0 + p1 + bias (fp32)
__global__ __launch_bounds__(256) void combine_kernel(
    const float* __restrict__ res, const float* __restrict__ p0,
    const float* __restrict__ p1, const float* __restrict__ bias,
    float* __restrict__ out) {
  size_t i = (size_t)blockIdx.x * 256 + threadIdx.x;
  float4 a = reinterpret_cast<const float4*>(res)[i];
  float4 c0 = reinterpret_cast<const float4*>(p0)[i];
  float4 c1 = reinterpret_cast<const float4*>(p1)[i];
  int col = (int)((i * 4) & (H - 1));
  float4 bb = *reinterpret_cast<const float4*>(bias + col);
  float4 o;
  o.x = a.x + c0.x + c1.x + bb.x;
  o.y = a.y + c0.y + c1.y + bb.y;
  o.z = a.z + c0.z + c1.z + bb.z;
  o.w = a.w + c0.w + c1.w + bb.w;
  reinterpret_cast<float4*>(out)[i] = o;
}

// fused: xout = res + p0 + p1 + bias (fp32) ; lnout = bf16(LN(xout))
__global__ __launch_bounds__(256) void combine_ln_kernel(
    const float* __restrict__ res, const float* __restrict__ p0,
    const float* __restrict__ p1, const float* __restrict__ bias,
    const float* __restrict__ lw, const float* __restrict__ lb,
    float* __restrict__ xout, ushort* __restrict__ lnout) {
  int row = blockIdx.x, t = threadIdx.x;
  const float4* rr = reinterpret_cast<const float4*>(res + (size_t)row * H);
  const float4* r0 = reinterpret_cast<const float4*>(p0 + (size_t)row * H);
  const float4* r1 = reinterpret_cast<const float4*>(p1 + (size_t)row * H);
  const float4* bb = reinterpret_cast<const float4*>(bias);
  float4 a0 = rr[t * 2], a1 = rr[t * 2 + 1];
  float4 c0 = r0[t * 2], c1 = r0[t * 2 + 1];
  float4 d0 = r1[t * 2], d1 = r1[t * 2 + 1];
  float4 e0 = bb[t * 2], e1 = bb[t * 2 + 1];
  float4 v0, v1;
  v0.x = a0.x + c0.x + d0.x + e0.x;
  v0.y = a0.y + c0.y + d0.y + e0.y;
  v0.z = a0.z + c0.z + d0.z + e0.z;
  v0.w = a0.w + c0.w + d0.w + e0.w;
  v1.x = a1.x + c1.x + d1.x + e1.x;
  v1.y = a1.y + c1.y + d1.y + e1.y;
  v1.z = a1.z + c1.z + d1.z + e1.z;
  v1.w = a1.w + c1.w + d1.w + e1.w;
  float4* xo = reinterpret_cast<float4*>(xout + (size_t)row * H);
  xo[t * 2] = v0;
  xo[t * 2 + 1] = v1;
  float s = v0.x + v0.y + v0.z + v0.w + v1.x + v1.y + v1.z + v1.w;
  float q = v0.x * v0.x + v0.y * v0.y + v0.z * v0.z + v0.w * v0.w +
            v1.x * v1.x + v1.y * v1.y + v1.z * v1.z + v1.w * v1.w;
#pragma unroll
  for (int off = 32; off > 0; off >>= 1) {
    s += __shfl_down(s, off, 64);
    q += __shfl_down(q, off, 64);
  }
  __shared__ float sm[8];
  int lane = t & 63, wv = t >> 6;
  if (lane == 0) { sm[wv] = s; sm[wv + 4] = q; }
  __syncthreads();
  s = sm[0] + sm[1] + sm[2] + sm[3];
  q = sm[4] + sm[5] + sm[6] + sm[7];
  float mu = s * (1.0f / H);
  float var = q * (1.0f / H) - mu * mu;
  float rs = rsqrtf(var + 1e-5f);
  const float4* wr = reinterpret_cast<const float4*>(lw);
  const float4* br = reinterpret_cast<const float4*>(lb);
  float4 w0 = wr[t * 2], w1v = wr[t * 2 + 1], b0 = br[t * 2], b1v = br[t * 2 + 1];
  short8 pk;
  pk[0] = (short)f2bf((v0.x - mu) * rs * w0.x + b0.x);
  pk[1] = (short)f2bf((v0.y - mu) * rs * w0.y + b0.y);
  pk[2] = (short)f2bf((v0.z - mu) * rs * w0.z + b0.z);
  pk[3] = (short)f2bf((v0.w - mu) * rs * w0.w + b0.w);
  pk[4] = (short)f2bf((v1.x - mu) * rs * w1v.x + b1v.x);
  pk[5] = (short)f2bf((v1.y - mu) * rs * w1v.y + b1v.y);
  pk[6] = (short)f2bf((v1.z - mu) * rs * w1v.z + b1v.z);
  pk[7] = (short)f2bf((v1.w - mu) * rs * w1v.w + b1v.w);
  *reinterpret_cast<short8*>(lnout + (size_t)row * H + t * 8) = pk;
}

// bf16 MFMA GEMM, 2-phase prefetch + XCD swizzle. C = A[M,lda] @ Bt[N,lda]^T
template <int MODE>
__global__ __launch_bounds__(256) void gemm_kernel(
    const ushort* __restrict__ A, const ushort* __restrict__ Bt,
    const float* __restrict__ bias,
    ushort* __restrict__ outb, float* __restrict__ outf,
    int M, int N, int lda, int kbeg, int klen) {
  __shared__ __align__(16) ushort As[2][128 * 32];
  __shared__ __align__(16) ushort Bs[2][128 * 32];
  int tid = threadIdx.x;
  int lane = tid & 63, wave = tid >> 6;
  int gx = gridDim.x, nwg = gx * gridDim.y;
  int orig = blockIdx.y * gx + blockIdx.x;
  int wg = (orig & 7) * (nwg >> 3) + (orig >> 3);
  int m0 = (wg % gx) * 128, n0 = (wg / gx) * 128;
  int wm = (wave >> 1) * 64, wn = (wave & 1) * 64;
  int lm = lane & 15, kg = lane >> 4;
  int kb0 = kbeg + blockIdx.z * klen;

  f32x4 acc[4][4] = {};

  int srow = lane >> 2;
  int scol = (lane & 3) * 8;
  const ushort* ga0 = A + (size_t)(m0 + wave * 32 + srow) * lda + kb0 + scol;
  const ushort* ga1 = A + (size_t)(m0 + wave * 32 + 16 + srow) * lda + kb0 + scol;
  const ushort* gb0 = Bt + (size_t)(n0 + wave * 32 + srow) * lda + kb0 + scol;
  const ushort* gb1 = Bt + (size_t)(n0 + wave * 32 + 16 + srow) * lda + kb0 + scol;

  gl_lds16(ga0, &As[0][wave * 1024]);
  gl_lds16(ga1, &As[0][wave * 1024 + 512]);
  gl_lds16(gb0, &Bs[0][wave * 1024]);
  gl_lds16(gb1, &Bs[0][wave * 1024 + 512]);
  __syncthreads();

  for (int k0 = 0; k0 < klen; k0 += 32) {
    int cur = (k0 >> 5) & 1;
    int nxt = cur ^ 1;
    if (k0 + 32 < klen) {
      gl_lds16(ga0 + k0 + 32, &As[nxt][wave * 1024]);
      gl_lds16(ga1 + k0 + 32, &As[nxt][wave * 1024 + 512]);
      gl_lds16(gb0 + k0 + 32, &Bs[nxt][wave * 1024]);
      gl_lds16(gb1 + k0 + 32, &Bs[nxt][wave * 1024 + 512]);
    }
    short8 af[4], bfr[4];
#pragma unroll
    for (int i = 0; i < 4; i++)
      af[i] = *reinterpret_cast<const short8*>(&As[cur][(wm + i * 16 + lm) * 32 + kg * 8]);
#pragma unroll
    for (int j = 0; j < 4; j++)
      bfr[j] = *reinterpret_cast<const short8*>(&Bs[cur][(wn + j * 16 + lm) * 32 + kg * 8]);
#pragma unroll
    for (int i = 0; i < 4; i++)
#pragma unroll
      for (int j = 0; j < 4; j++)
        acc[i][j] = __builtin_amdgcn_mfma_f32_16x16x32_bf16(af[i], bfr[j], acc[i][j], 0, 0, 0);
    __syncthreads();
  }

#pragma unroll
  for (int i = 0; i < 4; i++) {
#pragma unroll
    for (int j = 0; j < 4; j++) {
#pragma unroll
      for (int r = 0; r < 4; r++) {
        int row = m0 + wm + i * 16 + kg * 4 + r;
        int col = n0 + wn + j * 16 + lm;
        float v = acc[i][j][r];
        if (MODE == 0) {
          float t = v + bias[col];
          float sc = (col < H) ? 0.125f : 1.0f;
          size_t idx = (size_t)(col >> 11) * ((size_t)S * H) + (size_t)row * H + (col & (H - 1));
          outb[idx] = f2bf(t * sc);
        } else if (MODE == 1) {
          float t = v + bias[col];
          outb[(size_t)row * N + col] = f2bf(0.5f * t * (1.0f + erff(t * 0.70710678118f)));
        } else {
          outf[(size_t)blockIdx.z * M * N + (size_t)row * N + col] = v;
        }
      }
    }
  }
}

// causal flash attention, folded q-pair scheduling.
// Block (h, x): q-blocks {x, 15-x} of 128 rows; 8 waves x 16 q-rows; KVB=128 dbuf.
__global__ __launch_bounds__(512) void attn_kernel(
    const ushort* __restrict__ Q, const ushort* __restrict__ Kmat,
    const ushort* __restrict__ VT, ushort* __restrict__ ctx) {
  __shared__ __align__(16) ushort Ks[2][128 * 64];
  __shared__ __align__(16) ushort Vs[2][64 * 128];
  __shared__ __align__(16) ushort Ps[8 * 16 * 64];
  int h = blockIdx.x;
  int x = blockIdx.y;
  int tid = threadIdx.x, lane = tid & 63, w = tid >> 6;
  int lm = lane & 15, kg = lane >> 4;

  int qbA = x, qbB = 15 - x;
  int tA = x + 1;
  const int nt = 17;

  short8 qa[2];
#pragma unroll
  for (int ks = 0; ks < 2; ks++)
    qa[ks] = *reinterpret_cast<const short8*>(
        Q + (size_t)(qbA * 128 + w * 16 + lm) * H + h * 64 + ks * 32 + kg * 8);

  float m_run[4], l_run[4];
  f32x4 o_acc[4] = {};
#pragma unroll
  for (int r = 0; r < 4; r++) { m_run[r] = -1e30f; l_run[r] = 0.f; }

  auto stage = [&](int kb, int buf) {
#pragma unroll
    for (int p = 0; p < 2; p++) {
      int gbase = p * 512 + w * 64;
      int gran = gbase + lane;
      int krow = gran >> 3, gk = gran & 7;
      gl_lds16(Kmat + (size_t)(kb * 128 + krow) * H + h * 64 + ((gk ^ (krow & 7)) << 3),
               &Ks[buf][gbase * 8]);
    }
#pragma unroll
    for (int p = 0; p < 2; p++) {
      int gbase = p * 512 + w * 64;
      int gran = gbase + lane;
      int vrow = gran >> 4, gv = gran & 15;
      gl_lds16(VT + (size_t)(h * 64 + vrow) * S + kb * 128 + ((gv ^ (vrow & 15)) << 3),
               &Vs[buf][gbase * 8]);
    }
  };

  stage(0, 0);
  __syncthreads();

  for (int t = 0; t < nt; t++) {
    int cur = t & 1;
    if (t + 1 < nt) {
      int tn = t + 1;
      stage((tn < tA) ? tn : tn - tA, cur ^ 1);
    }
    bool diag = (t == tA - 1) || (t == nt - 1);

    f32x4 sacc[8] = {};
#pragma unroll
    for (int j = 0; j < 8; j++) {
      int krow = j * 16 + lm;
#pragma unroll
      for (int ks = 0; ks < 2; ks++) {
        short8 kf = *reinterpret_cast<const short8*>(
            &Ks[cur][krow * 64 + (((ks * 4 + kg) ^ (lm & 7)) << 3)]);
        sacc[j] = __builtin_amdgcn_mfma_f32_16x16x32_bf16(qa[ks], kf, sacc[j], 0, 0, 0);
      }
    }
    if (diag) {
#pragma unroll
      for (int j = 0; j < 8; j++)
#pragma unroll
        for (int r = 0; r < 4; r++)
          if (j * 16 + lm > w * 16 + kg * 4 + r) sacc[j][r] = -1e30f;
    }

#pragma unroll
    for (int r = 0; r < 4; r++) {
      float mx = sacc[0][r];
#pragma unroll
      for (int j = 1; j < 8; j++) mx = fmaxf(mx, sacc[j][r]);
      mx = fmaxf(mx, __shfl_xor(mx, 1, 64));
      mx = fmaxf(mx, __shfl_xor(mx, 2, 64));
      mx = fmaxf(mx, __shfl_xor(mx, 4, 64));
      mx = fmaxf(mx, __shfl_xor(mx, 8, 64));
      float mnew = fmaxf(m_run[r], mx);
      float sc = __expf(m_run[r] - mnew);
      m_run[r] = mnew;
      float ps = 0.f;
#pragma unroll
      for (int j = 0; j < 8; j++) {
        float p = __expf(sacc[j][r] - mnew);
        sacc[j][r] = p;
        ps += p;
      }
      ps += __shfl_xor(ps, 1, 64);
      ps += __shfl_xor(ps, 2, 64);
      ps += __shfl_xor(ps, 4, 64);
      ps += __shfl_xor(ps, 8, 64);
      l_run[r] = l_run[r] * sc + ps;
#pragma unroll
      for (int jd = 0; jd < 4; jd++) o_acc[jd][r] *= sc;
    }

#pragma unroll
    for (int c = 0; c < 2; c++) {
#pragma unroll
      for (int jj = 0; jj < 4; jj++)
#pragma unroll
        for (int r = 0; r < 4; r++) {
          int rl = kg * 4 + r;
          int col = jj * 16 + lm;
          Ps[w * 1024 + rl * 64 + (((col >> 3) ^ (rl & 7)) << 3) + (col & 7)] =
              f2bf(sacc[c * 4 + jj][r]);
        }
      short8 pa[2];
#pragma unroll
      for (int ks = 0; ks < 2; ks++)
        pa[ks] = *reinterpret_cast<const short8*>(
            &Ps[w * 1024 + lm * 64 + (((ks * 4 + kg) ^ (lm & 7)) << 3)]);
#pragma unroll
      for (int jd = 0; jd < 4; jd++) {
        int d = jd * 16 + lm;
#pragma unroll
        for (int ks = 0; ks < 2; ks++) {
          short8 vf = *reinterpret_cast<const short8*>(
              &Vs[cur][d * 128 + (((c * 8 + ks * 4 + kg) ^ lm) << 3)]);
          o_acc[jd] = __builtin_amdgcn_mfma_f32_16x16x32_bf16(pa[ks], vf, o_acc[jd], 0, 0, 0);
        }
      }
    }

    if (t == tA - 1) {
      // flush stream A, switch to stream B
#pragma unroll
      for (int jd = 0; jd < 4; jd++)
#pragma unroll
        for (int r = 0; r < 4; r++)
          ctx[(size_t)(qbA * 128 + w * 16 + kg * 4 + r) * H + h * 64 + jd * 16 + lm] =
              f2bf(o_acc[jd][r] / l_run[r]);
#pragma unroll
      for (int r = 0; r < 4; r++) { m_run[r] = -1e30f; l_run[r] = 0.f; }
#pragma unroll
      for (int jd = 0; jd < 4; jd++) o_acc[jd] = f32x4{0.f, 0.f, 0.f, 0.f};
#pragma unroll
      for (int ks = 0; ks < 2; ks++)
        qa[ks] = *reinterpret_cast<const short8*>(
            Q + (size_t)(qbB * 128 + w * 16 + lm) * H + h * 64 + ks * 32 + kg * 8);
    }
    __syncthreads();
  }

#pragma unroll
  for (int jd = 0; jd < 4; jd++)
#pragma unroll
    for (int r = 0; r < 4; r++)
      ctx[(size_t)(qbB * 128 + w * 16 + kg * 4 + r) * H + h * 64 + jd * 16 + lm] =
          f2bf(o_acc[jd][r] / l_run[r]);
}

extern "C" void kernel_launch(void* const* d_in, const int* in_sizes, int n_in,
                              void* d_out, int out_size, void* d_ws, size_t ws_size,
                              hipStream_t stream) {
  const float* x = (const float*)d_in[0];
  const float* ln1w = (const float*)d_in[2];
  const float* ln1b = (const float*)d_in[3];
  const float* wq = (const float*)d_in[4];
  const float* bq = (const float*)d_in[5];
  const float* wk = (const float*)d_in[6];
  const float* bk = (const float*)d_in[7];
  const float* wv = (const float*)d_in[8];
  const float* bv = (const float*)d_in[9];
  const float* wo = (const float*)d_in[10];
  const float* bo = (const float*)d_in[11];
  const float* w1 = (const float*)d_in[12];
  const float* b1 = (const float*)d_in[13];
  const float* w2 = (const float*)d_in[14];
  const float* b2 = (const float*)d_in[15];
  const float* ln2w = (const float*)d_in[16];
  const float* ln2b = (const float*)d_in[17];
  float* out = (float*)d_out;

  char* ws = (char*)d_ws;
  const size_t MB = 1024 * 1024;
  const size_t SH = (size_t)S * H;
  ushort* WT_QKV = (ushort*)(ws);
  ushort* WT_O = (ushort*)(ws + 24 * MB);
  ushort* WT_1 = (ushort*)(ws + 32 * MB);
  ushort* WT_2 = (ushort*)(ws + 64 * MB);
  ushort* LNO = (ushort*)(ws + 96 * MB);
  ushort* QKVB = (ushort*)(ws + 104 * MB);
  ushort* VTb = (ushort*)(ws + 128 * MB);
  ushort* CTX = (ushort*)(ws + 136 * MB);
  float* X1 = (float*)(ws + 144 * MB);
  float* BIASQ = (float*)(ws + 160 * MB);
  ushort* MID = (ushort*)(ws);
  float* SP = (float*)(ws + 104 * MB);

  transpose_cast_kernel<<<dim3(H / 64, H / 64), 256, 0, stream>>>(wq, WT_QKV, H, H);
  transpose_cast_kernel<<<dim3(H / 64, H / 64), 256, 0, stream>>>(wk, WT_QKV + SH, H, H);
  transpose_cast_kernel<<<dim3(H / 64, H / 64), 256, 0, stream>>>(wv, WT_QKV + 2 * SH, H, H);
  transpose_cast_kernel<<<dim3(H / 64, H / 64), 256, 0, stream>>>(wo, WT_O, H, H);
  transpose_cast_kernel<<<dim3(DFF / 64, H / 64), 256, 0, stream>>>(w1, WT_1, H, DFF);
  transpose_cast_kernel<<<dim3(H / 64, DFF / 64), 256, 0, stream>>>(w2, WT_2, DFF, H);
  biascat_kernel<<<3 * H / 256, 256, 0, stream>>>(bq, bk, bv, BIASQ);

  ln_kernel<<<S, 256, 0, stream>>>(x, ln1w, ln1b, LNO);

  gemm_kernel<0><<<dim3(S / 128, 3 * H / 128), 256, 0, stream>>>(
      LNO, WT_QKV, BIASQ, QKVB, nullptr, S, 3 * H, H, 0, H);

  vtrans_kernel<<<dim3(S / 32, H / 32), 256, 0, stream>>>(QKVB + 2 * SH, VTb);

  attn_kernel<<<dim3(NH, 8), 512, 0, stream>>>(QKVB, QKVB + SH, VTb, CTX);

  gemm_kernel<3><<<dim3(S / 128, H / 128, 2), 256, 0, stream>>>(
      CTX, WT_O, nullptr, nullptr, SP, S, H, H, 0, H / 2);
  combine_ln_kernel<<<S, 256, 0, stream>>>(x, SP, SP + SH, bo, ln2w, ln2b, X1, LNO);

  gemm_kernel<1><<<dim3(S / 128, DFF / 128), 256, 0, stream>>>(
      LNO, WT_1, b1, MID, nullptr, S, DFF, H, 0, H);

  gemm_kernel<3><<<dim3(S / 128, H / 128, 2), 256, 0, stream>>>(
      MID, WT_2, nullptr, nullptr, SP, S, H, DFF, 0, DFF / 2);
  combine_kernel<<<SH / 1024, 256, 0, stream>>>(X1, SP, SP + SH, b2, out);
}

// Round 6
// 448.374 us; speedup vs baseline: 1.7395x; 1.1210x over previous
//
#include <hip/hip_runtime.h>
#include <math.h>

#define H 2048
#define S 2048
#define NH 32
#define HD 64
#define DFF 8192

typedef __attribute__((ext_vector_type(4))) float f32x4;
typedef __attribute__((ext_vector_type(8))) short short8;

static __device__ __forceinline__ ushort f2bf(float f) {
  unsigned u = __float_as_uint(f);
  u += 0x7fff + ((u >> 16) & 1);
  return (ushort)(u >> 16);
}

static __device__ __forceinline__ void gl_lds16(const ushort* g, ushort* l) {
  __builtin_amdgcn_global_load_lds(
      (__attribute__((address_space(1))) const void*)g,
      (__attribute__((address_space(3))) void*)l, 16, 0, 0);
}

// transpose + cast fp32 -> bf16. W: [K][N] fp32; Wt: [N][K] bf16. 64x64 tiles.
__global__ __launch_bounds__(256) void transpose_cast_kernel(
    const float* __restrict__ W, ushort* __restrict__ Wt, int K, int N) {
  __shared__ __align__(16) ushort tile[64][72];
  int n0 = blockIdx.x * 64, k0 = blockIdx.y * 64;
  int t = threadIdx.x;
  int lk = t >> 4;
  int ln4 = (t & 15) * 4;
#pragma unroll
  for (int p = 0; p < 4; p++) {
    int k = p * 16 + lk;
    float4 v = *reinterpret_cast<const float4*>(&W[(size_t)(k0 + k) * N + n0 + ln4]);
    float vv[4] = {v.x, v.y, v.z, v.w};
#pragma unroll
    for (int i = 0; i < 4; i++) {
      int row = ln4 + i;
      int slot = ((k >> 3) ^ (row & 7));
      tile[row][(slot << 3) + (k & 7)] = f2bf(vv[i]);
    }
  }
  __syncthreads();
  int n = t >> 2;
  int kq = (t & 3) * 8;
#pragma unroll
  for (int p = 0; p < 2; p++) {
    int kk = kq + p * 32;
    int slot = ((kk >> 3) ^ (n & 7));
    short8 o = *reinterpret_cast<const short8*>(&tile[n][slot << 3]);
    *reinterpret_cast<short8*>(&Wt[(size_t)(n0 + n) * K + k0 + kk]) = o;
  }
}

// bf16 transpose [S][H] -> [H][S]
__global__ __launch_bounds__(256) void vtrans_kernel(
    const ushort* __restrict__ V, ushort* __restrict__ VT) {
  __shared__ ushort tile[32][33];
  int s0 = blockIdx.x * 32, d0 = blockIdx.y * 32;
  int tx = threadIdx.x & 31, ty = threadIdx.x >> 5;
#pragma unroll
  for (int i = 0; i < 4; i++)
    tile[ty * 4 + i][tx] = V[(size_t)(s0 + ty * 4 + i) * H + d0 + tx];
  __syncthreads();
#pragma unroll
  for (int i = 0; i < 4; i++)
    VT[(size_t)(d0 + ty * 4 + i) * S + s0 + tx] = tile[tx][ty * 4 + i];
}

// concat bq|bk|bv into one 6144-float vector
__global__ __launch_bounds__(256) void biascat_kernel(
    const float* __restrict__ bq, const float* __restrict__ bk,
    const float* __restrict__ bv, float* __restrict__ o) {
  int t = blockIdx.x * 256 + threadIdx.x;
  o[t] = (t < H) ? bq[t] : (t < 2 * H) ? bk[t - H] : bv[t - 2 * H];
}

// LayerNorm fp32 -> bf16
__global__ __launch_bounds__(256) void ln_kernel(
    const float* __restrict__ x, const float* __restrict__ w,
    const float* __restrict__ b, ushort* __restrict__ out) {
  int row = blockIdx.x, t = threadIdx.x;
  const float4* xr = reinterpret_cast<const float4*>(x + (size_t)row * H);
  float4 v0 = xr[t * 2], v1 = xr[t * 2 + 1];
  float s = v0.x + v0.y + v0.z + v0.w + v1.x + v1.y + v1.z + v1.w;
  float q = v0.x * v0.x + v0.y * v0.y + v0.z * v0.z + v0.w * v0.w +
            v1.x * v1.x + v1.y * v1.y + v1.z * v1.z + v1.w * v1.w;
#pragma unroll
  for (int off = 32; off > 0; off >>= 1) {
    s += __shfl_down(s, off, 64);
    q += __shfl_down(q, off, 64);
  }
  __shared__ float sm[8];
  int lane = t & 63, wv = t >> 6;
  if (lane == 0) { sm[wv] = s; sm[wv + 4] = q; }
  __syncthreads();
  s = sm[0] + sm[1] + sm[2] + sm[3];
  q = sm[4] + sm[5] + sm[6] + sm[7];
  float mu = s * (1.0f / H);
  float var = q * (1.0f / H) - mu * mu;
  float rs = rsqrtf(var + 1e-5f);
  const float4* wr = reinterpret_cast<const float4*>(w);
  const float4* br = reinterpret_cast<const float4*>(b);
  float4 w0 = wr[t * 2], w1v = wr[t * 2 + 1], b0 = br[t * 2], b1v = br[t * 2 + 1];
  short8 pk;
  pk[0] = (short)f2bf((v0.x - mu) * rs * w0.x + b0.x);
  pk[1] = (short)f2bf((v0.y - mu) * rs * w0.y + b0.y);
  pk[2] = (short)f2bf((v0.z - mu) * rs * w0.z + b0.z);
  pk[3] = (short)f2bf((v0.w - mu) * rs * w0.w + b0.w);
  pk[4] = (short)f2bf((v1.x - mu) * rs * w1v.x + b1v.x);
  pk[5] = (short)f2bf((v1.y - mu) * rs * w1v.y + b1v.y);
  pk[6] = (short)f2bf((v1.z - mu) * rs * w1v.z + b1v.z);
  pk[7] = (short)f2bf((v1.w - mu) * rs * w1v.w + b1v.w);
  *reinterpret_cast<short8*>(out + (size_t)row * H + t * 8) = pk;
}

// out = res + p0 + p1 + p2 + p3 + bias (fp32)
__global__ __launch_bounds__(256) void combine4_kernel(
    const float* __restrict__ res, const float* __restrict__ p0,
    const float* __restrict__ p1, const float* __restrict__ p2,
    const float* __restrict__ p3, const float* __restrict__ bias,
    float* __restrict__ out) {
  size_t i = (size_t)blockIdx.x * 256 + threadIdx.x;
  float4 a = reinterpret_cast<const float4*>(res)[i];
  float4 c0 = reinterpret_cast<const float4*>(p0)[i];
  float4 c1 = reinterpret_cast<const float4*>(p1)[i];
  float4 c2 = reinterpret_cast<const float4*>(p2)[i];
  float4 c3 = reinterpret_cast<const float4*>(p3)[i];
  int col = (int)((i * 4) & (H - 1));
  float4 bb = *reinterpret_cast<const float4*>(bias + col);
  float4 o;
  o.x = a.x + c0.x + c1.x + c2.x + c3.x + bb.x;
  o.y = a.y + c0.y + c1.y + c2.y + c3.y + bb.y;
  o.z = a.z + c0.z + c1.z + c2.z + c3.z + bb.z;
  o.w = a.w + c0.w + c1.w + c2.w + c3.w + bb.w;
  reinterpret_cast<float4*>(out)[i] = o;
}

// fused: xout = res + p0 + p1 + bias (fp32) ; lnout = bf16(LN(xout))
__global__ __launch_bounds__(256) void combine_ln_kernel(
    const float* __restrict__ res, const float* __restrict__ p0,
    const float* __restrict__ p1, const float* __restrict__ bias,
    const float* __restrict__ lw, const float* __restrict__ lb,
    float* __restrict__ xout, ushort* __restrict__ lnout) {
  int row = blockIdx.x, t = threadIdx.x;
  const float4* rr = reinterpret_cast<const float4*>(res + (size_t)row * H);
  const float4* r0 = reinterpret_cast<const float4*>(p0 + (size_t)row * H);
  const float4* r1 = reinterpret_cast<const float4*>(p1 + (size_t)row * H);
  const float4* bb = reinterpret_cast<const float4*>(bias);
  float4 a0 = rr[t * 2], a1 = rr[t * 2 + 1];
  float4 c0 = r0[t * 2], c1 = r0[t * 2 + 1];
  float4 d0 = r1[t * 2], d1 = r1[t * 2 + 1];
  float4 e0 = bb[t * 2], e1 = bb[t * 2 + 1];
  float4 v0, v1;
  v0.x = a0.x + c0.x + d0.x + e0.x;
  v0.y = a0.y + c0.y + d0.y + e0.y;
  v0.z = a0.z + c0.z + d0.z + e0.z;
  v0.w = a0.w + c0.w + d0.w + e0.w;
  v1.x = a1.x + c1.x + d1.x + e1.x;
  v1.y = a1.y + c1.y + d1.y + e1.y;
  v1.z = a1.z + c1.z + d1.z + e1.z;
  v1.w = a1.w + c1.w + d1.w + e1.w;
  float4* xo = reinterpret_cast<float4*>(xout + (size_t)row * H);
  xo[t * 2] = v0;
  xo[t * 2 + 1] = v1;
  float s = v0.x + v0.y + v0.z + v0.w + v1.x + v1.y + v1.z + v1.w;
  float q = v0.x * v0.x + v0.y * v0.y + v0.z * v0.z + v0.w * v0.w +
            v1.x * v1.x + v1.y * v1.y + v1.z * v1.z + v1.w * v1.w;
#pragma unroll
  for (int off = 32; off > 0; off >>= 1) {
    s += __shfl_down(s, off, 64);
    q += __shfl_down(q, off, 64);
  }
  __shared__ float sm[8];
  int lane = t & 63, wv = t >> 6;
  if (lane == 0) { sm[wv] = s; sm[wv + 4] = q; }
  __syncthreads();
  s = sm[0] + sm[1] + sm[2] + sm[3];
  q = sm[4] + sm[5] + sm[6] + sm[7];
  float mu = s * (1.0f / H);
  float var = q * (1.0f / H) - mu * mu;
  float rs = rsqrtf(var + 1e-5f);
  const float4* wr = reinterpret_cast<const float4*>(lw);
  const float4* br = reinterpret_cast<const float4*>(lb);
  float4 w0 = wr[t * 2], w1v = wr[t * 2 + 1], b0 = br[t * 2], b1v = br[t * 2 + 1];
  short8 pk;
  pk[0] = (short)f2bf((v0.x - mu) * rs * w0.x + b0.x);
  pk[1] = (short)f2bf((v0.y - mu) * rs * w0.y + b0.y);
  pk[2] = (short)f2bf((v0.z - mu) * rs * w0.z + b0.z);
  pk[3] = (short)f2bf((v0.w - mu) * rs * w0.w + b0.w);
  pk[4] = (short)f2bf((v1.x - mu) * rs * w1v.x + b1v.x);
  pk[5] = (short)f2bf((v1.y - mu) * rs * w1v.y + b1v.y);
  pk[6] = (short)f2bf((v1.z - mu) * rs * w1v.z + b1v.z);
  pk[7] = (short)f2bf((v1.w - mu) * rs * w1v.w + b1v.w);
  *reinterpret_cast<short8*>(lnout + (size_t)row * H + t * 8) = pk;
}

// ---------------- 256x256 8-phase bf16 MFMA GEMM ----------------
// C = A[M,lda] @ Bt[N,lda]^T over k in [kbeg + z*klen, +klen). 8 waves (2Mx4N).
// LDS: 2 dbuf x (A 256x64 + B 256x64) bf16 = 128KB, granule XOR swizzle
// (gc ^= row&7), staged via global_load_lds with pre-swizzled SOURCE.
// Counted vmcnt(2) at iteration entry; raw s_barrier (no drain) throughout.
// MODE 0: QKV split write outb[(col>>11)*S*H + row*H + (col&2047)], Q cols scaled
// MODE 1: outb = bf16(gelu(acc+bias)) row-major [M][N]
// MODE 3: outf[zslot*M*N + row*N + col] = acc, zslot = z + ((z>>1)<<1)
template <int MODE>
__global__ __launch_bounds__(512, 2) void gemm256_kernel(
    const ushort* __restrict__ A, const ushort* __restrict__ Bt,
    const float* __restrict__ bias,
    ushort* __restrict__ outb, float* __restrict__ outf,
    int M, int N, int lda, int kbeg, int klen) {
  __shared__ __align__(16) ushort As[2][256 * 64];
  __shared__ __align__(16) ushort Bs[2][256 * 64];
  int tid = threadIdx.x, lane = tid & 63, w = tid >> 6;
  int lm = lane & 15, kg = lane >> 4;
  int wr = w >> 2, wc = w & 3;
  int gx = gridDim.x, nwg = gx * gridDim.y;
  int orig = blockIdx.y * gx + blockIdx.x;
  int wg = (orig & 7) * (nwg >> 3) + (orig >> 3);
  int m0 = (wg % gx) * 256, n0 = (wg / gx) * 256;
  int kb0 = kbeg + blockIdx.z * klen;

  f32x4 acc[8][4] = {};

  // staging: granule g = q*512 + tid; row = g>>3, source col pre-swizzled
  const ushort* srcA[4];
  const ushort* srcB[4];
  int dbase[4];
#pragma unroll
  for (int q = 0; q < 4; q++) {
    int g = q * 512 + tid;
    int row = g >> 3, gc = g & 7;
    int col = (gc ^ (row & 7)) << 3;
    srcA[q] = A + (size_t)(m0 + row) * lda + kb0 + col;
    srcB[q] = Bt + (size_t)(n0 + row) * lda + kb0 + col;
    dbase[q] = (q * 512 + w * 64) * 8;  // wave-uniform; HW adds lane*16B
  }

  int nK = klen >> 6;
  // prologue: tile 0 -> buf 0 (8 loads)
#pragma unroll
  for (int q = 0; q < 4; q++) gl_lds16(srcA[q], &As[0][dbase[q]]);
#pragma unroll
  for (int q = 0; q < 4; q++) gl_lds16(srcB[q], &Bs[0][dbase[q]]);

  for (int kt = 0; kt < nK; kt++) {
    int cur = kt & 1, nxt = cur ^ 1;
    bool hn = (kt + 1 < nK);
    int ko = (kt + 1) << 6;
    if (hn) {
      gl_lds16(srcA[0] + ko, &As[nxt][dbase[0]]);
      gl_lds16(srcA[1] + ko, &As[nxt][dbase[1]]);
      asm volatile("s_waitcnt vmcnt(2)" ::: "memory");
    } else {
      asm volatile("s_waitcnt vmcnt(0)" ::: "memory");
    }
    __builtin_amdgcn_s_barrier();

    short8 bf[4][2], af[4][2];
#pragma unroll
    for (int n = 0; n < 4; n++)
#pragma unroll
      for (int s = 0; s < 2; s++)
        bf[n][s] = *reinterpret_cast<const short8*>(
            &Bs[cur][(wc * 64 + n * 16 + lm) * 64 + (((s * 4 + kg) ^ (lm & 7)) << 3)]);
#pragma unroll
    for (int i = 0; i < 4; i++)
#pragma unroll
      for (int s = 0; s < 2; s++)
        af[i][s] = *reinterpret_cast<const short8*>(
            &As[cur][(wr * 128 + i * 16 + lm) * 64 + (((s * 4 + kg) ^ (lm & 7)) << 3)]);
    if (hn) {
      gl_lds16(srcA[2] + ko, &As[nxt][dbase[2]]);
      gl_lds16(srcA[3] + ko, &As[nxt][dbase[3]]);
    }
    __builtin_amdgcn_s_barrier();
    __builtin_amdgcn_s_setprio(1);
#pragma unroll
    for (int i = 0; i < 4; i++)
#pragma unroll
      for (int n = 0; n < 2; n++)
#pragma unroll
        for (int s = 0; s < 2; s++)
          acc[i][n] = __builtin_amdgcn_mfma_f32_16x16x32_bf16(af[i][s], bf[n][s], acc[i][n], 0, 0, 0);
    __builtin_amdgcn_s_setprio(0);
    __builtin_amdgcn_s_barrier();

    if (hn) {
      gl_lds16(srcB[0] + ko, &Bs[nxt][dbase[0]]);
      gl_lds16(srcB[1] + ko, &Bs[nxt][dbase[1]]);
    }
    __builtin_amdgcn_s_barrier();
    __builtin_amdgcn_s_setprio(1);
#pragma unroll
    for (int i = 0; i < 4; i++)
#pragma unroll
      for (int n = 2; n < 4; n++)
#pragma unroll
        for (int s = 0; s < 2; s++)
          acc[i][n] = __builtin_amdgcn_mfma_f32_16x16x32_bf16(af[i][s], bf[n][s], acc[i][n], 0, 0, 0);
    __builtin_amdgcn_s_setprio(0);
    __builtin_amdgcn_s_barrier();

    // phase 2: A half 1
#pragma unroll
    for (int i = 0; i < 4; i++)
#pragma unroll
      for (int s = 0; s < 2; s++)
        af[i][s] = *reinterpret_cast<const short8*>(
            &As[cur][(wr * 128 + 64 + i * 16 + lm) * 64 + (((s * 4 + kg) ^ (lm & 7)) << 3)]);
    if (hn) {
      gl_lds16(srcB[2] + ko, &Bs[nxt][dbase[2]]);
      gl_lds16(srcB[3] + ko, &Bs[nxt][dbase[3]]);
    }
    __builtin_amdgcn_s_barrier();
    __builtin_amdgcn_s_setprio(1);
#pragma unroll
    for (int i = 0; i < 4; i++)
#pragma unroll
      for (int n = 0; n < 2; n++)
#pragma unroll
        for (int s = 0; s < 2; s++)
          acc[4 + i][n] = __builtin_amdgcn_mfma_f32_16x16x32_bf16(af[i][s], bf[n][s], acc[4 + i][n], 0, 0, 0);
    __builtin_amdgcn_s_setprio(0);
    __builtin_amdgcn_s_barrier();
    __builtin_amdgcn_s_setprio(1);
#pragma unroll
    for (int i = 0; i < 4; i++)
#pragma unroll
      for (int n = 2; n < 4; n++)
#pragma unroll
        for (int s = 0; s < 2; s++)
          acc[4 + i][n] = __builtin_amdgcn_mfma_f32_16x16x32_bf16(af[i][s], bf[n][s], acc[4 + i][n], 0, 0, 0);
    __builtin_amdgcn_s_setprio(0);
    __builtin_amdgcn_s_barrier();  // protects buf[cur] before next-iter staging
  }

#pragma unroll
  for (int mi = 0; mi < 8; mi++) {
#pragma unroll
    for (int ni = 0; ni < 4; ni++) {
#pragma unroll
      for (int r = 0; r < 4; r++) {
        int row = m0 + wr * 128 + mi * 16 + kg * 4 + r;
        int col = n0 + wc * 64 + ni * 16 + lm;
        float v = acc[mi][ni][r];
        if (MODE == 0) {
          float t = v + bias[col];
          float sc = (col < H) ? 0.125f : 1.0f;
          size_t idx = (size_t)(col >> 11) * ((size_t)S * H) + (size_t)row * H + (col & (H - 1));
          outb[idx] = f2bf(t * sc);
        } else if (MODE == 1) {
          float t = v + bias[col];
          outb[(size_t)row * N + col] = f2bf(0.5f * t * (1.0f + erff(t * 0.70710678118f)));
        } else {
          int zs = blockIdx.z + ((blockIdx.z >> 1) << 1);
          outf[(size_t)zs * M * N + (size_t)row * N + col] = v;
        }
      }
    }
  }
}

// causal flash attention, folded q-pair scheduling.
// Block (h, x): q-blocks {x, 15-x} of 128 rows; 8 waves x 16 q-rows; KVB=128 dbuf.
__global__ __launch_bounds__(512) void attn_kernel(
    const ushort* __restrict__ Q, const ushort* __restrict__ Kmat,
    const ushort* __restrict__ VT, ushort* __restrict__ ctx) {
  __shared__ __align__(16) ushort Ks[2][128 * 64];
  __shared__ __align__(16) ushort Vs[2][64 * 128];
  __shared__ __align__(16) ushort Ps[8 * 16 * 64];
  int h = blockIdx.x;
  int x = blockIdx.y;
  int tid = threadIdx.x, lane = tid & 63, w = tid >> 6;
  int lm = lane & 15, kg = lane >> 4;

  int qbA = x, qbB = 15 - x;
  int tA = x + 1;
  const int nt = 17;

  short8 qa[2];
#pragma unroll
  for (int ks = 0; ks < 2; ks++)
    qa[ks] = *reinterpret_cast<const short8*>(
        Q + (size_t)(qbA * 128 + w * 16 + lm) * H + h * 64 + ks * 32 + kg * 8);

  float m_run[4], l_run[4];
  f32x4 o_acc[4] = {};
#pragma unroll
  for (int r = 0; r < 4; r++) { m_run[r] = -1e30f; l_run[r] = 0.f; }

  auto stage = [&](int kb, int buf) {
#pragma unroll
    for (int p = 0; p < 2; p++) {
      int gbase = p * 512 + w * 64;
      int gran = gbase + lane;
      int krow = gran >> 3, gk = gran & 7;
      gl_lds16(Kmat + (size_t)(kb * 128 + krow) * H + h * 64 + ((gk ^ (krow & 7)) << 3),
               &Ks[buf][gbase * 8]);
    }
#pragma unroll
    for (int p = 0; p < 2; p++) {
      int gbase = p * 512 + w * 64;
      int gran = gbase + lane;
      int vrow = gran >> 4, gv = gran & 15;
      gl_lds16(VT + (size_t)(h * 64 + vrow) * S + kb * 128 + ((gv ^ (vrow & 15)) << 3),
               &Vs[buf][gbase * 8]);
    }
  };

  stage(0, 0);
  __syncthreads();

  for (int t = 0; t < nt; t++) {
    int cur = t & 1;
    if (t + 1 < nt) {
      int tn = t + 1;
      stage((tn < tA) ? tn : tn - tA, cur ^ 1);
    }
    bool diag = (t == tA - 1) || (t == nt - 1);

    f32x4 sacc[8] = {};
#pragma unroll
    for (int j = 0; j < 8; j++) {
      int krow = j * 16 + lm;
#pragma unroll
      for (int ks = 0; ks < 2; ks++) {
        short8 kf = *reinterpret_cast<const short8*>(
            &Ks[cur][krow * 64 + (((ks * 4 + kg) ^ (lm & 7)) << 3)]);
        sacc[j] = __builtin_amdgcn_mfma_f32_16x16x32_bf16(qa[ks], kf, sacc[j], 0, 0, 0);
      }
    }
    if (diag) {
#pragma unroll
      for (int j = 0; j < 8; j++)
#pragma unroll
        for (int r = 0; r < 4; r++)
          if (j * 16 + lm > w * 16 + kg * 4 + r) sacc[j][r] = -1e30f;
    }

#pragma unroll
    for (int r = 0; r < 4; r++) {
      float mx = sacc[0][r];
#pragma unroll
      for (int j = 1; j < 8; j++) mx = fmaxf(mx, sacc[j][r]);
      mx = fmaxf(mx, __shfl_xor(mx, 1, 64));
      mx = fmaxf(mx, __shfl_xor(mx, 2, 64));
      mx = fmaxf(mx, __shfl_xor(mx, 4, 64));
      mx = fmaxf(mx, __shfl_xor(mx, 8, 64));
      float mnew = fmaxf(m_run[r], mx);
      float sc = __expf(m_run[r] - mnew);
      m_run[r] = mnew;
      float ps = 0.f;
#pragma unroll
      for (int j = 0; j < 8; j++) {
        float p = __expf(sacc[j][r] - mnew);
        sacc[j][r] = p;
        ps += p;
      }
      ps += __shfl_xor(ps, 1, 64);
      ps += __shfl_xor(ps, 2, 64);
      ps += __shfl_xor(ps, 4, 64);
      ps += __shfl_xor(ps, 8, 64);
      l_run[r] = l_run[r] * sc + ps;
#pragma unroll
      for (int jd = 0; jd < 4; jd++) o_acc[jd][r] *= sc;
    }

#pragma unroll
    for (int c = 0; c < 2; c++) {
#pragma unroll
      for (int jj = 0; jj < 4; jj++)
#pragma unroll
        for (int r = 0; r < 4; r++) {
          int rl = kg * 4 + r;
          int col = jj * 16 + lm;
          Ps[w * 1024 + rl * 64 + (((col >> 3) ^ (rl & 7)) << 3) + (col & 7)] =
              f2bf(sacc[c * 4 + jj][r]);
        }
      short8 pa[2];
#pragma unroll
      for (int ks = 0; ks < 2; ks++)
        pa[ks] = *reinterpret_cast<const short8*>(
            &Ps[w * 1024 + lm * 64 + (((ks * 4 + kg) ^ (lm & 7)) << 3)]);
#pragma unroll
      for (int jd = 0; jd < 4; jd++) {
        int d = jd * 16 + lm;
#pragma unroll
        for (int ks = 0; ks < 2; ks++) {
          short8 vf = *reinterpret_cast<const short8*>(
              &Vs[cur][d * 128 + (((c * 8 + ks * 4 + kg) ^ lm) << 3)]);
          o_acc[jd] = __builtin_amdgcn_mfma_f32_16x16x32_bf16(pa[ks], vf, o_acc[jd], 0, 0, 0);
        }
      }
    }

    if (t == tA - 1) {
#pragma unroll
      for (int jd = 0; jd < 4; jd++)
#pragma unroll
        for (int r = 0; r < 4; r++)
          ctx[(size_t)(qbA * 128 + w * 16 + kg * 4 + r) * H + h * 64 + jd * 16 + lm] =
              f2bf(o_acc[jd][r] / l_run[r]);
#pragma unroll
      for (int r = 0; r < 4; r++) { m_run[r] = -1e30f; l_run[r] = 0.f; }
#pragma unroll
      for (int jd = 0; jd < 4; jd++) o_acc[jd] = f32x4{0.f, 0.f, 0.f, 0.f};
#pragma unroll
      for (int ks = 0; ks < 2; ks++)
        qa[ks] = *reinterpret_cast<const short8*>(
            Q + (size_t)(qbB * 128 + w * 16 + lm) * H + h * 64 + ks * 32 + kg * 8);
    }
    __syncthreads();
  }

#pragma unroll
  for (int jd = 0; jd < 4; jd++)
#pragma unroll
    for (int r = 0; r < 4; r++)
      ctx[(size_t)(qbB * 128 + w * 16 + kg * 4 + r) * H + h * 64 + jd * 16 + lm] =
          f2bf(o_acc[jd][r] / l_run[r]);
}

extern "C" void kernel_launch(void* const* d_in, const int* in_sizes, int n_in,
                              void* d_out, int out_size, void* d_ws, size_t ws_size,
                              hipStream_t stream) {
  const float* x = (const float*)d_in[0];
  const float* ln1w = (const float*)d_in[2];
  const float* ln1b = (const float*)d_in[3];
  const float* wq = (const float*)d_in[4];
  const float* bq = (const float*)d_in[5];
  const float* wk = (const float*)d_in[6];
  const float* bk = (const float*)d_in[7];
  const float* wv = (const float*)d_in[8];
  const float* bv = (const float*)d_in[9];
  const float* wo = (const float*)d_in[10];
  const float* bo = (const float*)d_in[11];
  const float* w1 = (const float*)d_in[12];
  const float* b1 = (const float*)d_in[13];
  const float* w2 = (const float*)d_in[14];
  const float* b2 = (const float*)d_in[15];
  const float* ln2w = (const float*)d_in[16];
  const float* ln2b = (const float*)d_in[17];
  float* out = (float*)d_out;

  char* ws = (char*)d_ws;
  const size_t MB = 1024 * 1024;
  const size_t SH = (size_t)S * H;
  ushort* WT_QKV = (ushort*)(ws);               // 0-24MB, dead after QKV gemm
  ushort* WT_O = (ushort*)(ws + 24 * MB);       // 24-32
  ushort* WT_1 = (ushort*)(ws + 32 * MB);       // 32-64, dead after MLP1
  ushort* WT_2 = (ushort*)(ws + 64 * MB);       // 64-96
  ushort* LNO = (ushort*)(ws + 96 * MB);        // 96-104
  ushort* QKVB = (ushort*)(ws + 104 * MB);      // 104-128, dead after attn
  ushort* VTb = (ushort*)(ws + 128 * MB);       // 128-136, dead after attn
  ushort* CTX = (ushort*)(ws + 136 * MB);       // 136-144
  float* X1 = (float*)(ws + 144 * MB);          // 144-160
  float* BIASQ = (float*)(ws + 160 * MB);       // 160MB+24KB
  ushort* MID = (ushort*)(ws);                  // 0-32 (over dead WT_QKV+WT_O)
  float* SPA = (float*)(ws + 104 * MB);         // attn-out partials {0,1}: 104-136
  float* SPM = (float*)(ws + 32 * MB);          // MLP2 partials slots {0,1,4,5}: 32-64, 96-128

  transpose_cast_kernel<<<dim3(H / 64, H / 64), 256, 0, stream>>>(wq, WT_QKV, H, H);
  transpose_cast_kernel<<<dim3(H / 64, H / 64), 256, 0, stream>>>(wk, WT_QKV + SH, H, H);
  transpose_cast_kernel<<<dim3(H / 64, H / 64), 256, 0, stream>>>(wv, WT_QKV + 2 * SH, H, H);
  transpose_cast_kernel<<<dim3(H / 64, H / 64), 256, 0, stream>>>(wo, WT_O, H, H);
  transpose_cast_kernel<<<dim3(DFF / 64, H / 64), 256, 0, stream>>>(w1, WT_1, H, DFF);
  transpose_cast_kernel<<<dim3(H / 64, DFF / 64), 256, 0, stream>>>(w2, WT_2, DFF, H);
  biascat_kernel<<<3 * H / 256, 256, 0, stream>>>(bq, bk, bv, BIASQ);

  ln_kernel<<<S, 256, 0, stream>>>(x, ln1w, ln1b, LNO);

  gemm256_kernel<0><<<dim3(S / 256, 3 * H / 256), 512, 0, stream>>>(
      LNO, WT_QKV, BIASQ, QKVB, nullptr, S, 3 * H, H, 0, H);

  vtrans_kernel<<<dim3(S / 32, H / 32), 256, 0, stream>>>(QKVB + 2 * SH, VTb);

  attn_kernel<<<dim3(NH, 8), 512, 0, stream>>>(QKVB, QKVB + SH, VTb, CTX);

  gemm256_kernel<3><<<dim3(S / 256, H / 256, 2), 512, 0, stream>>>(
      CTX, WT_O, nullptr, nullptr, SPA, S, H, H, 0, H / 2);
  combine_ln_kernel<<<S, 256, 0, stream>>>(x, SPA, SPA + SH, bo, ln2w, ln2b, X1, LNO);

  gemm256_kernel<1><<<dim3(S / 256, DFF / 256), 512, 0, stream>>>(
      LNO, WT_1, b1, MID, nullptr, S, DFF, H, 0, H);

  gemm256_kernel<3><<<dim3(S / 256, H / 256, 4), 512, 0, stream>>>(
      MID, WT_2, nullptr, nullptr, SPM, S, H, DFF, 0, DFF / 4);
  combine4_kernel<<<SH / 1024, 256, 0, stream>>>(
      X1, SPM, SPM + SH, SPM + 4 * SH, SPM + 5 * SH, b2, out);
}

// Round 7
// 438.598 us; speedup vs baseline: 1.7783x; 1.0223x over previous
//
#include <hip/hip_runtime.h>
#include <math.h>

#define H 2048
#define S 2048
#define NH 32
#define HD 64
#define DFF 8192

typedef __attribute__((ext_vector_type(4))) float f32x4;
typedef __attribute__((ext_vector_type(8))) short short8;

static __device__ __forceinline__ ushort f2bf(float f) {
  unsigned u = __float_as_uint(f);
  u += 0x7fff + ((u >> 16) & 1);
  return (ushort)(u >> 16);
}

static __device__ __forceinline__ void gl_lds16(const ushort* g, ushort* l) {
  __builtin_amdgcn_global_load_lds(
      (__attribute__((address_space(1))) const void*)g,
      (__attribute__((address_space(3))) void*)l, 16, 0, 0);
}

// transpose + cast fp32 -> bf16. W: [K][N] fp32; Wt: [N][K] bf16. 64x64 tiles.
__global__ __launch_bounds__(256) void transpose_cast_kernel(
    const float* __restrict__ W, ushort* __restrict__ Wt, int K, int N) {
  __shared__ __align__(16) ushort tile[64][72];
  int n0 = blockIdx.x * 64, k0 = blockIdx.y * 64;
  int t = threadIdx.x;
  int lk = t >> 4;
  int ln4 = (t & 15) * 4;
#pragma unroll
  for (int p = 0; p < 4; p++) {
    int k = p * 16 + lk;
    float4 v = *reinterpret_cast<const float4*>(&W[(size_t)(k0 + k) * N + n0 + ln4]);
    float vv[4] = {v.x, v.y, v.z, v.w};
#pragma unroll
    for (int i = 0; i < 4; i++) {
      int row = ln4 + i;
      int slot = ((k >> 3) ^ (row & 7));
      tile[row][(slot << 3) + (k & 7)] = f2bf(vv[i]);
    }
  }
  __syncthreads();
  int n = t >> 2;
  int kq = (t & 3) * 8;
#pragma unroll
  for (int p = 0; p < 2; p++) {
    int kk = kq + p * 32;
    int slot = ((kk >> 3) ^ (n & 7));
    short8 o = *reinterpret_cast<const short8*>(&tile[n][slot << 3]);
    *reinterpret_cast<short8*>(&Wt[(size_t)(n0 + n) * K + k0 + kk]) = o;
  }
}

// bf16 transpose [S][H] -> [H][S]
__global__ __launch_bounds__(256) void vtrans_kernel(
    const ushort* __restrict__ V, ushort* __restrict__ VT) {
  __shared__ ushort tile[32][33];
  int s0 = blockIdx.x * 32, d0 = blockIdx.y * 32;
  int tx = threadIdx.x & 31, ty = threadIdx.x >> 5;
#pragma unroll
  for (int i = 0; i < 4; i++)
    tile[ty * 4 + i][tx] = V[(size_t)(s0 + ty * 4 + i) * H + d0 + tx];
  __syncthreads();
#pragma unroll
  for (int i = 0; i < 4; i++)
    VT[(size_t)(d0 + ty * 4 + i) * S + s0 + tx] = tile[tx][ty * 4 + i];
}

// concat bq|bk|bv into one 6144-float vector
__global__ __launch_bounds__(256) void biascat_kernel(
    const float* __restrict__ bq, const float* __restrict__ bk,
    const float* __restrict__ bv, float* __restrict__ o) {
  int t = blockIdx.x * 256 + threadIdx.x;
  o[t] = (t < H) ? bq[t] : (t < 2 * H) ? bk[t - H] : bv[t - 2 * H];
}

// LayerNorm fp32 -> bf16
__global__ __launch_bounds__(256) void ln_kernel(
    const float* __restrict__ x, const float* __restrict__ w,
    const float* __restrict__ b, ushort* __restrict__ out) {
  int row = blockIdx.x, t = threadIdx.x;
  const float4* xr = reinterpret_cast<const float4*>(x + (size_t)row * H);
  float4 v0 = xr[t * 2], v1 = xr[t * 2 + 1];
  float s = v0.x + v0.y + v0.z + v0.w + v1.x + v1.y + v1.z + v1.w;
  float q = v0.x * v0.x + v0.y * v0.y + v0.z * v0.z + v0.w * v0.w +
            v1.x * v1.x + v1.y * v1.y + v1.z * v1.z + v1.w * v1.w;
#pragma unroll
  for (int off = 32; off > 0; off >>= 1) {
    s += __shfl_down(s, off, 64);
    q += __shfl_down(q, off, 64);
  }
  __shared__ float sm[8];
  int lane = t & 63, wv = t >> 6;
  if (lane == 0) { sm[wv] = s; sm[wv + 4] = q; }
  __syncthreads();
  s = sm[0] + sm[1] + sm[2] + sm[3];
  q = sm[4] + sm[5] + sm[6] + sm[7];
  float mu = s * (1.0f / H);
  float var = q * (1.0f / H) - mu * mu;
  float rs = rsqrtf(var + 1e-5f);
  const float4* wr = reinterpret_cast<const float4*>(w);
  const float4* br = reinterpret_cast<const float4*>(b);
  float4 w0 = wr[t * 2], w1v = wr[t * 2 + 1], b0 = br[t * 2], b1v = br[t * 2 + 1];
  short8 pk;
  pk[0] = (short)f2bf((v0.x - mu) * rs * w0.x + b0.x);
  pk[1] = (short)f2bf((v0.y - mu) * rs * w0.y + b0.y);
  pk[2] = (short)f2bf((v0.z - mu) * rs * w0.z + b0.z);
  pk[3] = (short)f2bf((v0.w - mu) * rs * w0.w + b0.w);
  pk[4] = (short)f2bf((v1.x - mu) * rs * w1v.x + b1v.x);
  pk[5] = (short)f2bf((v1.y - mu) * rs * w1v.y + b1v.y);
  pk[6] = (short)f2bf((v1.z - mu) * rs * w1v.z + b1v.z);
  pk[7] = (short)f2bf((v1.w - mu) * rs * w1v.w + b1v.w);
  *reinterpret_cast<short8*>(out + (size_t)row * H + t * 8) = pk;
}

// out = res + p0 + p1 + p2 + p3 + bias (fp32)
__global__ __launch_bounds__(256) void combine4_kernel(
    const float* __restrict__ res, const float* __restrict__ p0,
    const float* __restrict__ p1, const float* __restrict__ p2,
    const float* __restrict__ p3, const float* __restrict__ bias,
    float* __restrict__ out) {
  size_t i = (size_t)blockIdx.x * 256 + threadIdx.x;
  float4 a = reinterpret_cast<const float4*>(res)[i];
  float4 c0 = reinterpret_cast<const float4*>(p0)[i];
  float4 c1 = reinterpret_cast<const float4*>(p1)[i];
  float4 c2 = reinterpret_cast<const float4*>(p2)[i];
  float4 c3 = reinterpret_cast<const float4*>(p3)[i];
  int col = (int)((i * 4) & (H - 1));
  float4 bb = *reinterpret_cast<const float4*>(bias + col);
  float4 o;
  o.x = a.x + c0.x + c1.x + c2.x + c3.x + bb.x;
  o.y = a.y + c0.y + c1.y + c2.y + c3.y + bb.y;
  o.z = a.z + c0.z + c1.z + c2.z + c3.z + bb.z;
  o.w = a.w + c0.w + c1.w + c2.w + c3.w + bb.w;
  reinterpret_cast<float4*>(out)[i] = o;
}

// fused: xout = res + p0 + p1 + bias (fp32) ; lnout = bf16(LN(xout))
__global__ __launch_bounds__(256) void combine_ln_kernel(
    const float* __restrict__ res, const float* __restrict__ p0,
    const float* __restrict__ p1, const float* __restrict__ bias,
    const float* __restrict__ lw, const float* __restrict__ lb,
    float* __restrict__ xout, ushort* __restrict__ lnout) {
  int row = blockIdx.x, t = threadIdx.x;
  const float4* rr = reinterpret_cast<const float4*>(res + (size_t)row * H);
  const float4* r0 = reinterpret_cast<const float4*>(p0 + (size_t)row * H);
  const float4* r1 = reinterpret_cast<const float4*>(p1 + (size_t)row * H);
  const float4* bb = reinterpret_cast<const float4*>(bias);
  float4 a0 = rr[t * 2], a1 = rr[t * 2 + 1];
  float4 c0 = r0[t * 2], c1 = r0[t * 2 + 1];
  float4 d0 = r1[t * 2], d1 = r1[t * 2 + 1];
  float4 e0 = bb[t * 2], e1 = bb[t * 2 + 1];
  float4 v0, v1;
  v0.x = a0.x + c0.x + d0.x + e0.x;
  v0.y = a0.y + c0.y + d0.y + e0.y;
  v0.z = a0.z + c0.z + d0.z + e0.z;
  v0.w = a0.w + c0.w + d0.w + e0.w;
  v1.x = a1.x + c1.x + d1.x + e1.x;
  v1.y = a1.y + c1.y + d1.y + e1.y;
  v1.z = a1.z + c1.z + d1.z + e1.z;
  v1.w = a1.w + c1.w + d1.w + e1.w;
  float4* xo = reinterpret_cast<float4*>(xout + (size_t)row * H);
  xo[t * 2] = v0;
  xo[t * 2 + 1] = v1;
  float s = v0.x + v0.y + v0.z + v0.w + v1.x + v1.y + v1.z + v1.w;
  float q = v0.x * v0.x + v0.y * v0.y + v0.z * v0.z + v0.w * v0.w +
            v1.x * v1.x + v1.y * v1.y + v1.z * v1.z + v1.w * v1.w;
#pragma unroll
  for (int off = 32; off > 0; off >>= 1) {
    s += __shfl_down(s, off, 64);
    q += __shfl_down(q, off, 64);
  }
  __shared__ float sm[8];
  int lane = t & 63, wv = t >> 6;
  if (lane == 0) { sm[wv] = s; sm[wv + 4] = q; }
  __syncthreads();
  s = sm[0] + sm[1] + sm[2] + sm[3];
  q = sm[4] + sm[5] + sm[6] + sm[7];
  float mu = s * (1.0f / H);
  float var = q * (1.0f / H) - mu * mu;
  float rs = rsqrtf(var + 1e-5f);
  const float4* wr = reinterpret_cast<const float4*>(lw);
  const float4* br = reinterpret_cast<const float4*>(lb);
  float4 w0 = wr[t * 2], w1v = wr[t * 2 + 1], b0 = br[t * 2], b1v = br[t * 2 + 1];
  short8 pk;
  pk[0] = (short)f2bf((v0.x - mu) * rs * w0.x + b0.x);
  pk[1] = (short)f2bf((v0.y - mu) * rs * w0.y + b0.y);
  pk[2] = (short)f2bf((v0.z - mu) * rs * w0.z + b0.z);
  pk[3] = (short)f2bf((v0.w - mu) * rs * w0.w + b0.w);
  pk[4] = (short)f2bf((v1.x - mu) * rs * w1v.x + b1v.x);
  pk[5] = (short)f2bf((v1.y - mu) * rs * w1v.y + b1v.y);
  pk[6] = (short)f2bf((v1.z - mu) * rs * w1v.z + b1v.z);
  pk[7] = (short)f2bf((v1.w - mu) * rs * w1v.w + b1v.w);
  *reinterpret_cast<short8*>(lnout + (size_t)row * H + t * 8) = pk;
}

// ---------------- 256x256 deep-pipelined bf16 MFMA GEMM ----------------
// C = A[M,lda] @ Bt[N,lda]^T over k in [kbeg + z*klen, +klen). 8 waves (2Mx4N).
// LDS: 2 dbuf x (A 256x64 + B 256x64) bf16 = 128KB, granule XOR swizzle
// (gc ^= row&7), staged via global_load_lds with pre-swizzled SOURCE.
// All 8 next-tile loads issued at iteration START -> vmcnt(8) wait distance
// = one full iteration. Only 2 barriers per iteration (entry / exit).
// MODE 0: QKV split write outb[(col>>11)*S*H + row*H + (col&2047)], Q cols scaled
// MODE 1: outb = bf16(gelu(acc+bias)) row-major [M][N]
// MODE 3: outf[zslot*M*N + row*N + col] = acc, zslot = z + ((z>>1)<<1)
template <int MODE>
__global__ __launch_bounds__(512, 2) void gemm256_kernel(
    const ushort* __restrict__ A, const ushort* __restrict__ Bt,
    const float* __restrict__ bias,
    ushort* __restrict__ outb, float* __restrict__ outf,
    int M, int N, int lda, int kbeg, int klen) {
  __shared__ __align__(16) ushort As[2][256 * 64];
  __shared__ __align__(16) ushort Bs[2][256 * 64];
  int tid = threadIdx.x, lane = tid & 63, w = tid >> 6;
  int lm = lane & 15, kg = lane >> 4;
  int wr = w >> 2, wc = w & 3;
  int gx = gridDim.x, nwg = gx * gridDim.y;
  int orig = blockIdx.y * gx + blockIdx.x;
  int wg = (orig & 7) * (nwg >> 3) + (orig >> 3);
  int m0 = (wg % gx) * 256, n0 = (wg / gx) * 256;
  int kb0 = kbeg + blockIdx.z * klen;

  f32x4 acc[8][4] = {};

  // staging: granule g = q*512 + tid; row = g>>3, source col pre-swizzled
  const ushort* srcA[4];
  const ushort* srcB[4];
  int dbase[4];
#pragma unroll
  for (int q = 0; q < 4; q++) {
    int g = q * 512 + tid;
    int row = g >> 3, gc = g & 7;
    int col = (gc ^ (row & 7)) << 3;
    srcA[q] = A + (size_t)(m0 + row) * lda + kb0 + col;
    srcB[q] = Bt + (size_t)(n0 + row) * lda + kb0 + col;
    dbase[q] = (q * 512 + w * 64) * 8;  // wave-uniform; HW adds lane*16B
  }

  int nK = klen >> 6;
  // prologue: tile 0 -> buf 0 (8 loads)
#pragma unroll
  for (int q = 0; q < 4; q++) gl_lds16(srcA[q], &As[0][dbase[q]]);
#pragma unroll
  for (int q = 0; q < 4; q++) gl_lds16(srcB[q], &Bs[0][dbase[q]]);

  for (int kt = 0; kt < nK; kt++) {
    int cur = kt & 1, nxt = cur ^ 1;
    bool hn = (kt + 1 < nK);
    int ko = (kt + 1) << 6;
    if (hn) {
      // issue ALL next-tile loads up front -> full-iteration wait distance
      gl_lds16(srcA[0] + ko, &As[nxt][dbase[0]]);
      gl_lds16(srcA[1] + ko, &As[nxt][dbase[1]]);
      gl_lds16(srcA[2] + ko, &As[nxt][dbase[2]]);
      gl_lds16(srcA[3] + ko, &As[nxt][dbase[3]]);
      gl_lds16(srcB[0] + ko, &Bs[nxt][dbase[0]]);
      gl_lds16(srcB[1] + ko, &Bs[nxt][dbase[1]]);
      gl_lds16(srcB[2] + ko, &Bs[nxt][dbase[2]]);
      gl_lds16(srcB[3] + ko, &Bs[nxt][dbase[3]]);
      asm volatile("s_waitcnt vmcnt(8)" ::: "memory");
    } else {
      asm volatile("s_waitcnt vmcnt(0)" ::: "memory");
    }
    __builtin_amdgcn_s_barrier();  // all waves' tile-kt slices visible

    short8 bf[4][2], af[4][2], ag[4][2];
#pragma unroll
    for (int n = 0; n < 4; n++)
#pragma unroll
      for (int s = 0; s < 2; s++)
        bf[n][s] = *reinterpret_cast<const short8*>(
            &Bs[cur][(wc * 64 + n * 16 + lm) * 64 + (((s * 4 + kg) ^ (lm & 7)) << 3)]);
#pragma unroll
    for (int i = 0; i < 4; i++)
#pragma unroll
      for (int s = 0; s < 2; s++)
        af[i][s] = *reinterpret_cast<const short8*>(
            &As[cur][(wr * 128 + i * 16 + lm) * 64 + (((s * 4 + kg) ^ (lm & 7)) << 3)]);

    __builtin_amdgcn_s_setprio(1);
#pragma unroll
    for (int i = 0; i < 4; i++)
#pragma unroll
      for (int n = 0; n < 2; n++)
#pragma unroll
        for (int s = 0; s < 2; s++)
          acc[i][n] = __builtin_amdgcn_mfma_f32_16x16x32_bf16(af[i][s], bf[n][s], acc[i][n], 0, 0, 0);
    __builtin_amdgcn_s_setprio(0);

    // prefetch A half 1 while cluster1 runs on registers
#pragma unroll
    for (int i = 0; i < 4; i++)
#pragma unroll
      for (int s = 0; s < 2; s++)
        ag[i][s] = *reinterpret_cast<const short8*>(
            &As[cur][(wr * 128 + 64 + i * 16 + lm) * 64 + (((s * 4 + kg) ^ (lm & 7)) << 3)]);

    __builtin_amdgcn_s_setprio(1);
#pragma unroll
    for (int i = 0; i < 4; i++)
#pragma unroll
      for (int n = 2; n < 4; n++)
#pragma unroll
        for (int s = 0; s < 2; s++)
          acc[i][n] = __builtin_amdgcn_mfma_f32_16x16x32_bf16(af[i][s], bf[n][s], acc[i][n], 0, 0, 0);
    __builtin_amdgcn_s_setprio(0);

    __builtin_amdgcn_s_setprio(1);
#pragma unroll
    for (int i = 0; i < 4; i++)
#pragma unroll
      for (int n = 0; n < 2; n++)
#pragma unroll
        for (int s = 0; s < 2; s++)
          acc[4 + i][n] = __builtin_amdgcn_mfma_f32_16x16x32_bf16(ag[i][s], bf[n][s], acc[4 + i][n], 0, 0, 0);
    __builtin_amdgcn_s_setprio(0);

    __builtin_amdgcn_s_setprio(1);
#pragma unroll
    for (int i = 0; i < 4; i++)
#pragma unroll
      for (int n = 2; n < 4; n++)
#pragma unroll
        for (int s = 0; s < 2; s++)
          acc[4 + i][n] = __builtin_amdgcn_mfma_f32_16x16x32_bf16(ag[i][s], bf[n][s], acc[4 + i][n], 0, 0, 0);
    __builtin_amdgcn_s_setprio(0);

    __builtin_amdgcn_s_barrier();  // all reads of buf[cur] done before next-iter staging
  }

#pragma unroll
  for (int mi = 0; mi < 8; mi++) {
#pragma unroll
    for (int ni = 0; ni < 4; ni++) {
#pragma unroll
      for (int r = 0; r < 4; r++) {
        int row = m0 + wr * 128 + mi * 16 + kg * 4 + r;
        int col = n0 + wc * 64 + ni * 16 + lm;
        float v = acc[mi][ni][r];
        if (MODE == 0) {
          float t = v + bias[col];
          float sc = (col < H) ? 0.125f : 1.0f;
          size_t idx = (size_t)(col >> 11) * ((size_t)S * H) + (size_t)row * H + (col & (H - 1));
          outb[idx] = f2bf(t * sc);
        } else if (MODE == 1) {
          float t = v + bias[col];
          outb[(size_t)row * N + col] = f2bf(0.5f * t * (1.0f + erff(t * 0.70710678118f)));
        } else {
          int zs = blockIdx.z + ((blockIdx.z >> 1) << 1);
          outf[(size_t)zs * M * N + (size_t)row * N + col] = v;
        }
      }
    }
  }
}

// causal flash attention, folded q-pair scheduling.
// Block (h, x): q-blocks {x, 15-x} of 128 rows; 8 waves x 16 q-rows; KVB=128 dbuf.
__global__ __launch_bounds__(512) void attn_kernel(
    const ushort* __restrict__ Q, const ushort* __restrict__ Kmat,
    const ushort* __restrict__ VT, ushort* __restrict__ ctx) {
  __shared__ __align__(16) ushort Ks[2][128 * 64];
  __shared__ __align__(16) ushort Vs[2][64 * 128];
  __shared__ __align__(16) ushort Ps[8 * 16 * 64];
  int h = blockIdx.x;
  int x = blockIdx.y;
  int tid = threadIdx.x, lane = tid & 63, w = tid >> 6;
  int lm = lane & 15, kg = lane >> 4;

  int qbA = x, qbB = 15 - x;
  int tA = x + 1;
  const int nt = 17;

  short8 qa[2];
#pragma unroll
  for (int ks = 0; ks < 2; ks++)
    qa[ks] = *reinterpret_cast<const short8*>(
        Q + (size_t)(qbA * 128 + w * 16 + lm) * H + h * 64 + ks * 32 + kg * 8);

  float m_run[4], l_run[4];
  f32x4 o_acc[4] = {};
#pragma unroll
  for (int r = 0; r < 4; r++) { m_run[r] = -1e30f; l_run[r] = 0.f; }

  auto stage = [&](int kb, int buf) {
#pragma unroll
    for (int p = 0; p < 2; p++) {
      int gbase = p * 512 + w * 64;
      int gran = gbase + lane;
      int krow = gran >> 3, gk = gran & 7;
      gl_lds16(Kmat + (size_t)(kb * 128 + krow) * H + h * 64 + ((gk ^ (krow & 7)) << 3),
               &Ks[buf][gbase * 8]);
    }
#pragma unroll
    for (int p = 0; p < 2; p++) {
      int gbase = p * 512 + w * 64;
      int gran = gbase + lane;
      int vrow = gran >> 4, gv = gran & 15;
      gl_lds16(VT + (size_t)(h * 64 + vrow) * S + kb * 128 + ((gv ^ (vrow & 15)) << 3),
               &Vs[buf][gbase * 8]);
    }
  };

  stage(0, 0);
  __syncthreads();

  for (int t = 0; t < nt; t++) {
    int cur = t & 1;
    if (t + 1 < nt) {
      int tn = t + 1;
      stage((tn < tA) ? tn : tn - tA, cur ^ 1);
    }
    bool diag = (t == tA - 1) || (t == nt - 1);

    f32x4 sacc[8] = {};
#pragma unroll
    for (int j = 0; j < 8; j++) {
      int krow = j * 16 + lm;
#pragma unroll
      for (int ks = 0; ks < 2; ks++) {
        short8 kf = *reinterpret_cast<const short8*>(
            &Ks[cur][krow * 64 + (((ks * 4 + kg) ^ (lm & 7)) << 3)]);
        sacc[j] = __builtin_amdgcn_mfma_f32_16x16x32_bf16(qa[ks], kf, sacc[j], 0, 0, 0);
      }
    }
    if (diag) {
#pragma unroll
      for (int j = 0; j < 8; j++)
#pragma unroll
        for (int r = 0; r < 4; r++)
          if (j * 16 + lm > w * 16 + kg * 4 + r) sacc[j][r] = -1e30f;
    }

#pragma unroll
    for (int r = 0; r < 4; r++) {
      float mx = sacc[0][r];
#pragma unroll
      for (int j = 1; j < 8; j++) mx = fmaxf(mx, sacc[j][r]);
      mx = fmaxf(mx, __shfl_xor(mx, 1, 64));
      mx = fmaxf(mx, __shfl_xor(mx, 2, 64));
      mx = fmaxf(mx, __shfl_xor(mx, 4, 64));
      mx = fmaxf(mx, __shfl_xor(mx, 8, 64));
      float mnew = fmaxf(m_run[r], mx);
      float sc = __expf(m_run[r] - mnew);
      m_run[r] = mnew;
      float ps = 0.f;
#pragma unroll
      for (int j = 0; j < 8; j++) {
        float p = __expf(sacc[j][r] - mnew);
        sacc[j][r] = p;
        ps += p;
      }
      ps += __shfl_xor(ps, 1, 64);
      ps += __shfl_xor(ps, 2, 64);
      ps += __shfl_xor(ps, 4, 64);
      ps += __shfl_xor(ps, 8, 64);
      l_run[r] = l_run[r] * sc + ps;
#pragma unroll
      for (int jd = 0; jd < 4; jd++) o_acc[jd][r] *= sc;
    }

#pragma unroll
    for (int c = 0; c < 2; c++) {
#pragma unroll
      for (int jj = 0; jj < 4; jj++)
#pragma unroll
        for (int r = 0; r < 4; r++) {
          int rl = kg * 4 + r;
          int col = jj * 16 + lm;
          Ps[w * 1024 + rl * 64 + (((col >> 3) ^ (rl & 7)) << 3) + (col & 7)] =
              f2bf(sacc[c * 4 + jj][r]);
        }
      short8 pa[2];
#pragma unroll
      for (int ks = 0; ks < 2; ks++)
        pa[ks] = *reinterpret_cast<const short8*>(
            &Ps[w * 1024 + lm * 64 + (((ks * 4 + kg) ^ (lm & 7)) << 3)]);
#pragma unroll
      for (int jd = 0; jd < 4; jd++) {
        int d = jd * 16 + lm;
#pragma unroll
        for (int ks = 0; ks < 2; ks++) {
          short8 vf = *reinterpret_cast<const short8*>(
              &Vs[cur][d * 128 + (((c * 8 + ks * 4 + kg) ^ lm) << 3)]);
          o_acc[jd] = __builtin_amdgcn_mfma_f32_16x16x32_bf16(pa[ks], vf, o_acc[jd], 0, 0, 0);
        }
      }
    }

    if (t == tA - 1) {
#pragma unroll
      for (int jd = 0; jd < 4; jd++)
#pragma unroll
        for (int r = 0; r < 4; r++)
          ctx[(size_t)(qbA * 128 + w * 16 + kg * 4 + r) * H + h * 64 + jd * 16 + lm] =
              f2bf(o_acc[jd][r] / l_run[r]);
#pragma unroll
      for (int r = 0; r < 4; r++) { m_run[r] = -1e30f; l_run[r] = 0.f; }
#pragma unroll
      for (int jd = 0; jd < 4; jd++) o_acc[jd] = f32x4{0.f, 0.f, 0.f, 0.f};
#pragma unroll
      for (int ks = 0; ks < 2; ks++)
        qa[ks] = *reinterpret_cast<const short8*>(
            Q + (size_t)(qbB * 128 + w * 16 + lm) * H + h * 64 + ks * 32 + kg * 8);
    }
    __syncthreads();
  }

#pragma unroll
  for (int jd = 0; jd < 4; jd++)
#pragma unroll
    for (int r = 0; r < 4; r++)
      ctx[(size_t)(qbB * 128 + w * 16 + kg * 4 + r) * H + h * 64 + jd * 16 + lm] =
          f2bf(o_acc[jd][r] / l_run[r]);
}

extern "C" void kernel_launch(void* const* d_in, const int* in_sizes, int n_in,
                              void* d_out, int out_size, void* d_ws, size_t ws_size,
                              hipStream_t stream) {
  const float* x = (const float*)d_in[0];
  const float* ln1w = (const float*)d_in[2];
  const float* ln1b = (const float*)d_in[3];
  const float* wq = (const float*)d_in[4];
  const float* bq = (const float*)d_in[5];
  const float* wk = (const float*)d_in[6];
  const float* bk = (const float*)d_in[7];
  const float* wv = (const float*)d_in[8];
  const float* bv = (const float*)d_in[9];
  const float* wo = (const float*)d_in[10];
  const float* bo = (const float*)d_in[11];
  const float* w1 = (const float*)d_in[12];
  const float* b1 = (const float*)d_in[13];
  const float* w2 = (const float*)d_in[14];
  const float* b2 = (const float*)d_in[15];
  const float* ln2w = (const float*)d_in[16];
  const float* ln2b = (const float*)d_in[17];
  float* out = (float*)d_out;

  char* ws = (char*)d_ws;
  const size_t MB = 1024 * 1024;
  const size_t SH = (size_t)S * H;
  ushort* WT_QKV = (ushort*)(ws);               // 0-24MB, dead after QKV gemm
  ushort* WT_O = (ushort*)(ws + 24 * MB);       // 24-32
  ushort* WT_1 = (ushort*)(ws + 32 * MB);       // 32-64, dead after MLP1
  ushort* WT_2 = (ushort*)(ws + 64 * MB);       // 64-96
  ushort* LNO = (ushort*)(ws + 96 * MB);        // 96-104
  ushort* QKVB = (ushort*)(ws + 104 * MB);      // 104-128, dead after attn
  ushort* VTb = (ushort*)(ws + 128 * MB);       // 128-136, dead after attn
  ushort* CTX = (ushort*)(ws + 136 * MB);       // 136-144
  float* X1 = (float*)(ws + 144 * MB);          // 144-160
  float* BIASQ = (float*)(ws + 160 * MB);       // 160MB+24KB
  ushort* MID = (ushort*)(ws);                  // 0-32 (over dead WT_QKV+WT_O)
  float* SPA = (float*)(ws + 104 * MB);         // attn-out partials {0,1}: 104-136
  float* SPM = (float*)(ws + 32 * MB);          // MLP2 partials slots {0,1,4,5}: 32-64, 96-128

  transpose_cast_kernel<<<dim3(H / 64, H / 64), 256, 0, stream>>>(wq, WT_QKV, H, H);
  transpose_cast_kernel<<<dim3(H / 64, H / 64), 256, 0, stream>>>(wk, WT_QKV + SH, H, H);
  transpose_cast_kernel<<<dim3(H / 64, H / 64), 256, 0, stream>>>(wv, WT_QKV + 2 * SH, H, H);
  transpose_cast_kernel<<<dim3(H / 64, H / 64), 256, 0, stream>>>(wo, WT_O, H, H);
  transpose_cast_kernel<<<dim3(DFF / 64, H / 64), 256, 0, stream>>>(w1, WT_1, H, DFF);
  transpose_cast_kernel<<<dim3(H / 64, DFF / 64), 256, 0, stream>>>(w2, WT_2, DFF, H);
  biascat_kernel<<<3 * H / 256, 256, 0, stream>>>(bq, bk, bv, BIASQ);

  ln_kernel<<<S, 256, 0, stream>>>(x, ln1w, ln1b, LNO);

  gemm256_kernel<0><<<dim3(S / 256, 3 * H / 256), 512, 0, stream>>>(
      LNO, WT_QKV, BIASQ, QKVB, nullptr, S, 3 * H, H, 0, H);

  vtrans_kernel<<<dim3(S / 32, H / 32), 256, 0, stream>>>(QKVB + 2 * SH, VTb);

  attn_kernel<<<dim3(NH, 8), 512, 0, stream>>>(QKVB, QKVB + SH, VTb, CTX);

  gemm256_kernel<3><<<dim3(S / 256, H / 256, 2), 512, 0, stream>>>(
      CTX, WT_O, nullptr, nullptr, SPA, S, H, H, 0, H / 2);
  combine_ln_kernel<<<S, 256, 0, stream>>>(x, SPA, SPA + SH, bo, ln2w, ln2b, X1, LNO);

  gemm256_kernel<1><<<dim3(S / 256, DFF / 256), 512, 0, stream>>>(
      LNO, WT_1, b1, MID, nullptr, S, DFF, H, 0, H);

  gemm256_kernel<3><<<dim3(S / 256, H / 256, 4), 512, 0, stream>>>(
      MID, WT_2, nullptr, nullptr, SPM, S, H, DFF, 0, DFF / 4);
  combine4_kernel<<<SH / 1024, 256, 0, stream>>>(
      X1, SPM, SPM + SH, SPM + 4 * SH, SPM + 5 * SH, b2, out);
}